// Round 24
// baseline (270.015 us; speedup 1.0000x reference)
//
#include <hip/hip_runtime.h>
#include <hip/hip_bf16.h>
#include <math.h>

#define NP 8192
#define KN 32

typedef __attribute__((ext_vector_type(8))) short short8v;   // 8 bf16
typedef __attribute__((ext_vector_type(4))) short short4v;   // 4 bf16
typedef __attribute__((ext_vector_type(4))) float f32x4v;
typedef __attribute__((ext_vector_type(16))) float f32x16v;

__device__ __forceinline__ float sgnf(float x){ return (x>0.f)?1.f:((x<0.f)?-1.f:0.f); }
__device__ __forceinline__ unsigned short f2bf(float f){
  unsigned u = __float_as_uint(f);
  unsigned r = (u + 0x7FFFu + ((u>>16)&1u)) >> 16;
  return (unsigned short)r;
}
__device__ __forceinline__ unsigned short f2bf_n(float f){
  __hip_bfloat16 h = __float2bfloat16(f);
  return reinterpret_cast<unsigned short&>(h);
}
__device__ __forceinline__ float bf2f(unsigned short u){ return __uint_as_float(((unsigned)u)<<16); }

// compute compressed geometry {w, tx, ty, tz} for (query n, neighbor nb)
__device__ __forceinline__ float4 geo_compute(const float* __restrict__ pos2, int n, int nb){
  const float R = 0.5f * (float)(1.5*6.0*0.025);
  float x = (pos2[nb*3+0]-pos2[n*3+0])/R;
  float y = (pos2[nb*3+1]-pos2[n*3+1])/R;
  float z = (pos2[nb*3+2]-pos2[n*3+2])/R;
  float sq = x*x+y*y+z*z;
  float wgt = 0.f;
  if (sq < 1.f){ float t1 = 1.f-sq; wgt = t1*t1*t1; }
  if (nb == n) wgt = 0.f;
  const float eps = 1e-8f;
  float norm = sqrtf(sq);
  float sq_xy = x*x+y*y;
  bool polar = 1.25f*z*z > sq_xy;
  float sa = sqrtf(3.f*norm/(norm+fabsf(z)+eps));
  float sb = norm/(sqrtf(sq_xy)+eps);
  float xc = polar ? x*sa : x*sb;
  float yc = polar ? y*sa : y*sb;
  float zc = polar ? sgnf(z)*norm : 1.5f*z;
  if (sq < eps){ xc=x; yc=y; zc=z; }
  float nxy = sqrtf(xc*xc+yc*yc);
  const float fo_pi = (float)(4.0/3.141592653589793);
  float sx = (fabsf(xc)>eps) ? xc : eps;
  float sy = (fabsf(yc)>eps) ? yc : eps;
  float ux = sgnf(xc)*nxy;
  float vv = sgnf(yc)*nxy;
  bool xbig = fabsf(yc) <= fabsf(xc);
  float u = xbig ? ux : vv*fo_pi*atanf(xc/sy);
  float v = xbig ? ux*fo_pi*atanf(yc/sx) : vv;
  if (nxy < eps){ u = xc; v = yc; }
  float tx = fminf(fmaxf((u  + 1.f)*1.5f, 0.f), 3.f);
  float ty = fminf(fmaxf((v  + 1.f)*1.5f, 0.f), 3.f);
  float tz = fminf(fmaxf((zc + 1.f)*1.5f, 0.f), 3.f);
  return make_float4(wgt, tx, ty, tz);
}

__device__ __forceinline__ void corners_from_geo(float4 g, float* gg, int* bb){
  float tx=g.y, ty=g.z, tz=g.w, w=g.x;
  int ix = (int)floorf(tx); ix = ix>2?2:ix;
  int iy = (int)floorf(ty); iy = iy>2?2:iy;
  int iz = (int)floorf(tz); iz = iz>2?2:iz;
  float fx = tx-(float)ix, fy = ty-(float)iy, fz = tz-(float)iz;
  float wxa[2] = {1.f-fx, fx};
  float wya[2] = {1.f-fy, fy};
  float wza[2] = {1.f-fz, fz};
  int b000 = ix*16 + iy*4 + iz;
  #pragma unroll
  for (int cc=0; cc<8; cc++){
    int cx = cc>>2, cy = (cc>>1)&1, cz = cc&1;
    gg[cc] = w * wxa[cx]*wya[cy]*wza[cz];
    bb[cc] = b000 + cx*16 + cy*4 + cz;
  }
}

// ---------------- prep + weight transpose fused ----------------
__global__ __launch_bounds__(256) void k_prepw(const float* __restrict__ pos, const float* __restrict__ vel,
    float* __restrict__ pos2, float* __restrict__ feats4,
    const float* __restrict__ W1, const float* __restrict__ W2,
    unsigned short* __restrict__ WT1, unsigned short* __restrict__ WT2){
  __shared__ unsigned short tile[64][72];
  int t = threadIdx.x;
  if (blockIdx.x < 32){
    int i = blockIdx.x*256 + t;
    const float DT = 0.02f;
    float vx = vel[i*3+0], vy = vel[i*3+1], vz = vel[i*3+2];
    float v2x = vx;
    float v2y = vy + DT*(-9.81f);
    float v2z = vz;
    float px = pos[i*3+0] + (DT*(v2x+vx))*0.5f;
    float py = pos[i*3+1] + (DT*(v2y+vy))*0.5f;
    float pz = pos[i*3+2] + (DT*(v2z+vz))*0.5f;
    pos2[i*3+0]=px; pos2[i*3+1]=py; pos2[i*3+2]=pz;
    feats4[i*4+0]=1.f; feats4[i*4+1]=v2x; feats4[i*4+2]=v2y; feats4[i*4+3]=v2z;
    return;
  }
  int b2 = blockIdx.x - 32;
  const float* W = (b2 < 64) ? W1 : W2;
  unsigned short* WT = (b2 < 64) ? WT1 : WT2;
  int kb = (b2 & 63)*64;
  {
    int co = t&63, kr = t>>6;
    #pragma unroll
    for (int i=0;i<16;i++){
      int k = i*4 + kr;
      tile[co][k] = f2bf(W[(size_t)(kb+k)*64 + co]);
    }
  }
  __syncthreads();
  {
    int kk = t&63, cor = t>>6;
    #pragma unroll
    for (int i=0;i<16;i++){
      int co2 = i*4 + cor;
      WT[(size_t)co2*4096 + kb + kk] = tile[co2][kk];
    }
  }
}

// ---------------- cconv0 + fused geometry ----------------
__global__ __launch_bounds__(256) void k_cconv0(const float* __restrict__ feats4, const int* __restrict__ nbrs,
    const float* __restrict__ pos2, float4* __restrict__ geo,
    const float* __restrict__ W0, const float* __restrict__ b0, float* __restrict__ a0f){
  __shared__ float CWT[4][64][33];
  __shared__ float Xs[4][32][4];
  __shared__ float Ws[8192];
  __shared__ float Bl[4][320];
  int t = threadIdx.x, lane = t&63, w = t>>6;
  int n = blockIdx.x*4 + w;
  #pragma unroll
  for (int i=0;i<32;i++) Ws[i*256+t] = W0[i*256+t];
  {
    float* cw = &CWT[w][0][0];
    #pragma unroll
    for (int i=0;i<33;i++) cw[i*64+lane] = 0.f;
  }
  if (lane < 32){
    int idx = n*KN + lane;
    int nb = nbrs[idx];
    *(float4*)&Xs[w][lane][0] = *(const float4*)(feats4 + (size_t)nb*4);
    float4 g = geo_compute(pos2, n, nb);
    geo[idx] = g;
    float gg[8]; int bb[8];
    corners_from_geo(g, gg, bb);
    __builtin_amdgcn_s_waitcnt(0);
    #pragma unroll
    for (int cc=0;cc<8;cc++) CWT[w][bb[cc]][lane] = gg[cc];
  }
  __syncthreads();
  float bacc0=0.f, bacc1=0.f, bacc2=0.f, bacc3=0.f;
  #pragma unroll 8
  for (int k=0;k<32;k++){
    float cw = CWT[w][lane][k];
    float4 xk = *(float4*)&Xs[w][k][0];
    bacc0 += cw*xk.x; bacc1 += cw*xk.y; bacc2 += cw*xk.z; bacc3 += cw*xk.w;
  }
  Bl[w][lane*5+0]=bacc0; Bl[w][lane*5+1]=bacc1; Bl[w][lane*5+2]=bacc2; Bl[w][lane*5+3]=bacc3;
  __syncthreads();
  {
    int h = lane>>5, co = lane&31;
    float acc = h ? 0.f : b0[co];
    int k0 = h*128;
    #pragma unroll 8
    for (int kk=0;kk<128;kk++){
      int kx = k0+kk;
      acc += Bl[w][(kx>>2)*5 + (kx&3)] * Ws[kx*32+co];
    }
    acc += __shfl_xor(acc, 32);
    if (h == 0) a0f[(size_t)n*32+co] = acc;
  }
}

// ---------------- LN(a0f) twice + bf16 Q1(scaled),K1,V1^T + Q2(scaled) ----------------
__global__ __launch_bounds__(128) void k_lnproj1(const float* __restrict__ a0f,
    const float* __restrict__ lna, const float* __restrict__ lnb,
    const float* __restrict__ selfW, const float* __restrict__ selfb,
    const float* __restrict__ srcW, const float* __restrict__ srcb,
    unsigned short* __restrict__ Qb1, unsigned short* __restrict__ Kb1,
    unsigned short* __restrict__ VT1, unsigned short* __restrict__ Q2b){
  __shared__ float sh[4][2][32];
  int t=threadIdx.x, rr=t>>5, c=t&31;
  int r = blockIdx.x*4+rr;
  float x = a0f[r*32+c];
  float s = x;
  for (int o=16;o;o>>=1) s += __shfl_xor(s,o,32);
  float mu = s*(1.f/32.f);
  float d = x-mu;
  float s2 = d*d;
  for (int o=16;o;o>>=1) s2 += __shfl_xor(s2,o,32);
  float istd = 1.f/(sqrtf(s2*(1.f/31.f))+1e-6f);
  sh[rr][0][c] = lna[c]*d*istd + lnb[c];
  sh[rr][1][c] = lna[32+c]*d*istd + lnb[32+c];
  __syncthreads();
  float aq = selfb[c], ak = selfb[32+c], av = selfb[64+c], aq2 = srcb[c];
  for (int cc=0;cc<32;cc++){
    float v0 = sh[rr][0][cc], v1 = sh[rr][1][cc];
    aq  += v0*selfW[cc*32+c];
    ak  += v0*selfW[1024+cc*32+c];
    av  += v0*selfW[2048+cc*32+c];
    aq2 += v1*srcW[cc*32+c];
  }
  const float scl = 0.17677669529663687f;
  Qb1[r*32+c] = f2bf(aq*scl);
  Kb1[r*32+c] = f2bf(ak);
  VT1[(size_t)c*8192 + r] = f2bf(av);
  Q2b[r*32+c] = f2bf(aq2*scl);
}

// ---------------- MFMA flash-attention: 64-key staged tiles, fixed-ref softmax, 8 partitions ----------------
__global__ __launch_bounds__(256) void k_attn_mfma(const unsigned short* __restrict__ Qb,
    const unsigned short* __restrict__ Kb, const unsigned short* __restrict__ VT,
    float* __restrict__ Pacc, float* __restrict__ Pml){
  __shared__ unsigned short Ks[2][64][40];
  __shared__ unsigned short Vs[2][32][72];
  __shared__ float Ot[4][16][36];
  int t = threadIdx.x, lane = t&63, w = t>>6;
  int qb = blockIdx.x, kp = blockIdx.y;
  int q0 = qb*64 + w*16;
  int l15 = lane&15, lg = lane>>4;
  short8v qf = *(const short8v*)(Qb + (size_t)(q0+l15)*32 + lg*8);
  f32x4v o0 = {0.f,0.f,0.f,0.f}, o1 = {0.f,0.f,0.f,0.f};
  f32x4v cz = {0.f,0.f,0.f,0.f};
  const float M0 = 8.f;
  float lacc = 0.f;
  int kbase = kp*1024;

#define STAGE(KT, BUF) do {                                                     \
    int _kb = kbase + (KT)*64;                                                  \
    if (t < 128){                                                               \
      int _row = t>>1, _seg = t&1;                                              \
      const unsigned short* _src = Kb + (size_t)(_kb+_row)*32 + _seg*16;        \
      uint4 _u0 = *(const uint4*)_src;                                          \
      uint4 _u1 = *(const uint4*)(_src+8);                                      \
      *(uint4*)&Ks[BUF][_row][_seg*16]   = _u0;                                 \
      *(uint4*)&Ks[BUF][_row][_seg*16+8] = _u1;                                 \
    } else {                                                                    \
      int _tt = t-128; int _dim = _tt>>2, _seg = _tt&3;                         \
      const unsigned short* _src = VT + (size_t)_dim*8192 + _kb + _seg*16;      \
      uint4 _u0 = *(const uint4*)_src;                                          \
      uint4 _u1 = *(const uint4*)(_src+8);                                      \
      *(uint4*)&Vs[BUF][_dim][_seg*16]   = _u0;                                 \
      *(uint4*)&Vs[BUF][_dim][_seg*16+8] = _u1;                                 \
    }                                                                           \
  } while(0)

  STAGE(0, 0);
  __syncthreads();
  for (int kt=0; kt<16; kt++){
    int b = kt&1;
    if (kt < 15) STAGE(kt+1, b^1);
    #pragma unroll
    for (int h=0; h<2; h++){
      int kk = h*32;
      short8v kf0 = *(const short8v*)&Ks[b][kk+l15][lg*8];
      short8v kf1 = *(const short8v*)&Ks[b][kk+16+l15][lg*8];
      short4v v0a = *(const short4v*)&Vs[b][l15][kk+lg*4];
      short4v v0b = *(const short4v*)&Vs[b][l15][kk+16+lg*4];
      short4v v1a = *(const short4v*)&Vs[b][16+l15][kk+lg*4];
      short4v v1b = *(const short4v*)&Vs[b][16+l15][kk+16+lg*4];
      f32x4v sa = __builtin_amdgcn_mfma_f32_16x16x32_bf16(kf0, qf, cz, 0,0,0);
      f32x4v sb = __builtin_amdgcn_mfma_f32_16x16x32_bf16(kf1, qf, cz, 0,0,0);
      float p0 = __expf(fminf(sa[0]-M0, 30.f)), p1 = __expf(fminf(sa[1]-M0, 30.f));
      float p2 = __expf(fminf(sa[2]-M0, 30.f)), p3 = __expf(fminf(sa[3]-M0, 30.f));
      float p4 = __expf(fminf(sb[0]-M0, 30.f)), p5 = __expf(fminf(sb[1]-M0, 30.f));
      float p6 = __expf(fminf(sb[2]-M0, 30.f)), p7 = __expf(fminf(sb[3]-M0, 30.f));
      lacc += (p0+p1)+(p2+p3)+(p4+p5)+(p6+p7);
      ushort4 ppa, ppb;
      ppa.x = f2bf_n(p0); ppa.y = f2bf_n(p1); ppa.z = f2bf_n(p2); ppa.w = f2bf_n(p3);
      ppb.x = f2bf_n(p4); ppb.y = f2bf_n(p5); ppb.z = f2bf_n(p6); ppb.w = f2bf_n(p7);
      short4v pfa = *(short4v*)&ppa;
      short4v pfb = *(short4v*)&ppb;
      o0 = __builtin_amdgcn_mfma_f32_16x16x16bf16_1k(v0a, pfa, o0, 0,0,0);
      o0 = __builtin_amdgcn_mfma_f32_16x16x16bf16_1k(v0b, pfb, o0, 0,0,0);
      o1 = __builtin_amdgcn_mfma_f32_16x16x16bf16_1k(v1a, pfa, o1, 0,0,0);
      o1 = __builtin_amdgcn_mfma_f32_16x16x16bf16_1k(v1b, pfb, o1, 0,0,0);
    }
    __syncthreads();
  }
#undef STAGE
  lacc += __shfl_xor(lacc, 16);
  lacc += __shfl_xor(lacc, 32);
  #pragma unroll
  for (int r=0;r<4;r++){
    Ot[w][l15][lg*4+r] = o0[r];
    Ot[w][l15][16+lg*4+r] = o1[r];
  }
  __builtin_amdgcn_s_waitcnt(0);
  {
    size_t pi = ((size_t)(q0+l15)*8 + kp)*32;
    float4 a = *(float4*)&Ot[w][l15][lg*8];
    float4 b = *(float4*)&Ot[w][l15][lg*8+4];
    *(float4*)(Pacc + pi + lg*8)     = a;
    *(float4*)(Pacc + pi + lg*8 + 4) = b;
    if (lg == 0){
      Pml[((size_t)(q0+l15)*8 + kp)*2 + 0] = M0;
      Pml[((size_t)(q0+l15)*8 + kp)*2 + 1] = lacc;
    }
  }
}

// ---------------- merge1 ----------------
__global__ __launch_bounds__(128) void k_merge1(const float* __restrict__ Pacc, const float* __restrict__ Pml,
    const float* __restrict__ resid, const float* __restrict__ Wo, const float* __restrict__ bo,
    const float* __restrict__ srcW, const float* __restrict__ srcb,
    unsigned short* __restrict__ Kb2, unsigned short* __restrict__ VT2){
  __shared__ float sh[4][32];
  __shared__ float shh[4][32];
  int t=threadIdx.x, rr=t>>5, c=t&31;
  int r = blockIdx.x*4+rr;
  float m = -1e30f;
  for (int p=0;p<8;p++) m = fmaxf(m, Pml[(r*8+p)*2]);
  float l = 0.f, a = 0.f;
  for (int p=0;p<8;p++){
    float mp = Pml[(r*8+p)*2], lp = Pml[(r*8+p)*2+1];
    float sc = expf(mp-m);
    l += lp*sc;
    a += Pacc[(r*8+p)*32+c]*sc;
  }
  sh[rr][c] = a/l;
  __syncthreads();
  float acc = bo[c];
  for (int cc=0;cc<32;cc++) acc += sh[rr][cc]*Wo[cc*32+c];
  float h = resid[r*32+c] + acc;
  shh[rr][c] = h;
  __syncthreads();
  float ak = srcb[32+c], av = srcb[64+c];
  for (int cc=0;cc<32;cc++){
    float v = shh[rr][cc];
    ak += v*srcW[1024+cc*32+c];
    av += v*srcW[2048+cc*32+c];
  }
  Kb2[r*32+c] = f2bf(ak);
  VT2[(size_t)c*8192 + r] = f2bf(av);
}

// ---------------- merge2 ----------------
__global__ __launch_bounds__(128) void k_merge2(const float* __restrict__ Pacc, const float* __restrict__ Pml,
    const float* __restrict__ resid, const float* __restrict__ Wo, const float* __restrict__ bo,
    const float* __restrict__ lna, const float* __restrict__ lnb,
    const float* __restrict__ w1, const float* __restrict__ b1,
    const float* __restrict__ w2, const float* __restrict__ b2, float* __restrict__ x0){
  __shared__ float sh[4][32];
  __shared__ float sh2[4][64];
  int t=threadIdx.x, rr=t>>5, c=t&31;
  int r = blockIdx.x*4+rr;
  float m = -1e30f;
  for (int p=0;p<8;p++) m = fmaxf(m, Pml[(r*8+p)*2]);
  float l = 0.f, a = 0.f;
  for (int p=0;p<8;p++){
    float mp = Pml[(r*8+p)*2], lp = Pml[(r*8+p)*2+1];
    float sc = expf(mp-m);
    l += lp*sc;
    a += Pacc[(r*8+p)*32+c]*sc;
  }
  sh[rr][c] = a/l;
  __syncthreads();
  float acc = bo[c];
  for (int cc=0;cc<32;cc++) acc += sh[rr][cc]*Wo[cc*32+c];
  float x = resid[r*32+c] + acc;      // h2
  __syncthreads();
  float s = x;
  for (int o=16;o;o>>=1) s += __shfl_xor(s,o,32);
  float mu = s*(1.f/32.f);
  float d = x-mu;
  float s2 = d*d;
  for (int o=16;o;o>>=1) s2 += __shfl_xor(s2,o,32);
  float istd = 1.f/(sqrtf(s2*(1.f/31.f))+1e-6f);
  sh[rr][c] = lna[64+c]*d*istd + lnb[64+c];
  __syncthreads();
  #pragma unroll
  for (int jj=0;jj<2;jj++){
    int j = c + jj*32;
    float h = b1[j];
    for (int cc=0;cc<32;cc++) h += sh[rr][cc]*w1[cc*64+j];
    sh2[rr][j] = fmaxf(h, 0.f);
  }
  __syncthreads();
  #pragma unroll
  for (int jj=0;jj<2;jj++){
    int j = c + jj*32;
    float o = b2[j];
    for (int kk=0;kk<64;kk++) o += sh2[rr][kk]*w2[kk*64+j];
    x0[r*64+j] = o;
  }
}

// ---------------- build B via MFMA (atomic-free), full NP ----------------
__global__ __launch_bounds__(256) void k_build(const float* __restrict__ xin, const int* __restrict__ nbrs,
    const float4* __restrict__ geo, unsigned short* __restrict__ Bg){
  __shared__ unsigned short XT[4][2560];
  __shared__ unsigned short CWT[4][2560];
  int t = threadIdx.x, lane = t&63, w = t>>6;
  int n = blockIdx.x*4 + w;
  unsigned short* xt = XT[w];
  unsigned short* cwt = CWT[w];
  #pragma unroll
  for (int i=0;i<5;i++) ((uint4*)cwt)[i*64+lane] = make_uint4(0u,0u,0u,0u);
  int nreg = 0; float4 g = make_float4(0.f,0.f,0.f,0.f);
  if (lane < 32){
    nreg = nbrs[n*KN + lane];
    g = geo[(size_t)n*KN + lane];
  }
  float xv[32];
  #pragma unroll
  for (int k=0;k<32;k++){
    int nb = __shfl(nreg, k);
    xv[k] = xin[(size_t)nb*64 + lane];
  }
  #pragma unroll
  for (int k2=0;k2<16;k2++){
    unsigned lo = f2bf(fmaxf(xv[2*k2],   0.f));
    unsigned hi = f2bf(fmaxf(xv[2*k2+1], 0.f));
    *(unsigned*)&xt[lane*40 + 2*k2] = lo | (hi<<16);
  }
  if (lane < 32){
    float gg[8]; int bb[8];
    corners_from_geo(g, gg, bb);
    #pragma unroll
    for (int cc=0;cc<8;cc++) cwt[bb[cc]*40 + lane] = f2bf(gg[cc]);
  }
  int l31 = lane&31, lg = lane>>5;
  short8v af[2][2], bf[2][2];
  #pragma unroll
  for (int bt=0;bt<2;bt++)
    #pragma unroll
    for (int kc=0;kc<2;kc++)
      af[bt][kc] = *(short8v*)&cwt[(bt*32+l31)*40 + kc*16 + lg*8];
  #pragma unroll
  for (int ct=0;ct<2;ct++)
    #pragma unroll
    for (int kc=0;kc<2;kc++)
      bf[ct][kc] = *(short8v*)&xt[(ct*32+l31)*40 + kc*16 + lg*8];
  f32x16v acc[2][2];
  #pragma unroll
  for (int bt=0;bt<2;bt++)
    #pragma unroll
    for (int ct=0;ct<2;ct++){
      f32x16v z = {0.f,0.f,0.f,0.f,0.f,0.f,0.f,0.f,0.f,0.f,0.f,0.f,0.f,0.f,0.f,0.f};
      z = __builtin_amdgcn_mfma_f32_32x32x16_bf16(af[bt][0], bf[ct][0], z, 0,0,0);
      z = __builtin_amdgcn_mfma_f32_32x32x16_bf16(af[bt][1], bf[ct][1], z, 0,0,0);
      acc[bt][ct] = z;
    }
  unsigned short* dst = Bg + (size_t)n*4096;
  #pragma unroll
  for (int bt=0;bt<2;bt++)
    #pragma unroll
    for (int ct=0;ct<2;ct++)
      #pragma unroll
      for (int r=0;r<16;r++){
        int row = (r&3) + 8*(r>>2) + 4*lg;
        dst[(bt*32+row)*64 + ct*32 + l31] = f2bf(acc[bt][ct][r]);
      }
}

// ---------------- fused build + gemm3 + epilogue ----------------
__global__ __launch_bounds__(256) void k_buildgemm3(const float* __restrict__ xin, const int* __restrict__ nbrs,
    const float4* __restrict__ geo, const float* __restrict__ W3,
    const float* __restrict__ cb3, const float* __restrict__ dw3, const float* __restrict__ db3,
    const float* __restrict__ pos, const float* __restrict__ pos2, float* __restrict__ outp){
  __shared__ unsigned short XT[4][2560];
  __shared__ unsigned short CWT[4][2560];
  __shared__ unsigned short W3p[3][4096];
  int t = threadIdx.x, lane = t&63, w = t>>6;
  int n = blockIdx.x*4 + w;
  unsigned short* xt  = XT[w];
  unsigned short* cwt = CWT[w];
  #pragma unroll
  for (int co=0; co<3; co++)
    #pragma unroll
    for (int i=0;i<16;i++){
      int k = t + i*256;
      W3p[co][k] = f2bf(W3[(size_t)k*3 + co]);
    }
  #pragma unroll
  for (int i=0;i<5;i++) ((uint4*)cwt)[i*64+lane] = make_uint4(0u,0u,0u,0u);
  int nreg = 0; float4 g = make_float4(0.f,0.f,0.f,0.f);
  if (lane < 32){
    nreg = nbrs[n*KN + lane];
    g = geo[(size_t)n*KN + lane];
  }
  float xv[32];
  #pragma unroll
  for (int k=0;k<32;k++){
    int nb = __shfl(nreg, k);
    xv[k] = xin[(size_t)nb*64 + lane];
  }
  float xq = fmaxf(xin[(size_t)n*64 + lane], 0.f);
  float3 dwv;
  dwv.x = dw3[lane*3+0]; dwv.y = dw3[lane*3+1]; dwv.z = dw3[lane*3+2];
  #pragma unroll
  for (int k2=0;k2<16;k2++){
    unsigned lo = f2bf(fmaxf(xv[2*k2],   0.f));
    unsigned hi = f2bf(fmaxf(xv[2*k2+1], 0.f));
    *(unsigned*)&xt[lane*40 + 2*k2] = lo | (hi<<16);
  }
  if (lane < 32){
    float gg[8]; int bb[8];
    corners_from_geo(g, gg, bb);
    #pragma unroll
    for (int cc=0;cc<8;cc++) cwt[bb[cc]*40 + lane] = f2bf(gg[cc]);
  }
  __syncthreads();
  int l31 = lane&31, lg = lane>>5;
  short8v af[2][2], bf[2][2];
  #pragma unroll
  for (int bt=0;bt<2;bt++)
    #pragma unroll
    for (int kc=0;kc<2;kc++)
      af[bt][kc] = *(short8v*)&cwt[(bt*32+l31)*40 + kc*16 + lg*8];
  #pragma unroll
  for (int ct=0;ct<2;ct++)
    #pragma unroll
    for (int kc=0;kc<2;kc++)
      bf[ct][kc] = *(short8v*)&xt[(ct*32+l31)*40 + kc*16 + lg*8];
  f32x16v acc[2][2];
  #pragma unroll
  for (int bt=0;bt<2;bt++)
    #pragma unroll
    for (int ct=0;ct<2;ct++){
      f32x16v z = {0.f,0.f,0.f,0.f,0.f,0.f,0.f,0.f,0.f,0.f,0.f,0.f,0.f,0.f,0.f,0.f};
      z = __builtin_amdgcn_mfma_f32_32x32x16_bf16(af[bt][0], bf[ct][0], z, 0,0,0);
      z = __builtin_amdgcn_mfma_f32_32x32x16_bf16(af[bt][1], bf[ct][1], z, 0,0,0);
      acc[bt][ct] = z;
    }
  float y0 = xq*dwv.x, y1 = xq*dwv.y, y2 = xq*dwv.z;
  #pragma unroll
  for (int bt=0;bt<2;bt++)
    #pragma unroll
    for (int ct=0;ct<2;ct++)
      #pragma unroll
      for (int r=0;r<16;r++){
        int row = (r&3) + 8*(r>>2) + 4*lg;
        int k = (bt*32+row)*64 + ct*32 + l31;
        float b = bf2f(f2bf(acc[bt][ct][r]));
        y0 += b * bf2f(W3p[0][k]);
        y1 += b * bf2f(W3p[1][k]);
        y2 += b * bf2f(W3p[2][k]);
      }
  #pragma unroll
  for (int m=1; m<64; m<<=1){
    y0 += __shfl_xor(y0, m);
    y1 += __shfl_xor(y1, m);
    y2 += __shfl_xor(y2, m);
  }
  if (lane < 3){
    int co = lane;
    float y = (co==0 ? y0 : (co==1 ? y1 : y2)) + cb3[co] + db3[co];
    float pc = y*(1.f/128.f);
    float po = pos2[n*3+co] + pc;
    outp[n*3+co] = po;
    outp[NP*3 + n*3+co] = (po - pos[n*3+co]) / 0.02f;
  }
}

// ---------------- gemmB: K-split 16 (8 MFMA steps/wave), 8 blocks/CU = full residency ----------------
__global__ __launch_bounds__(256, 4) void k_gemmB(const unsigned short* __restrict__ Bg,
    const unsigned short* __restrict__ WT, float* __restrict__ partial){
  int t = threadIdx.x, lane = t&63, w = t>>6;
  int qt = blockIdx.x, kh = blockIdx.y;
  int l15 = lane&15, lg = lane>>4;
  int kbase = kh*256;
  const unsigned short* arow = Bg + (size_t)(qt*64 + w*16 + l15)*4096 + kbase + lg*8;
  const unsigned short* wt0 = WT + (size_t)l15*4096 + kbase + lg*8;
  f32x4v a0 = {0.f,0.f,0.f,0.f}, a1 = {0.f,0.f,0.f,0.f};
  f32x4v a2 = {0.f,0.f,0.f,0.f}, a3 = {0.f,0.f,0.f,0.f};
  short8v afn = *(const short8v*)(arow);
  short8v b0n = *(const short8v*)(wt0);
  short8v b1n = *(const short8v*)(wt0 + 16*4096);
  short8v b2n = *(const short8v*)(wt0 + 32*4096);
  short8v b3n = *(const short8v*)(wt0 + 48*4096);
  #pragma unroll
  for (int s=0;s<8;s++){
    short8v af = afn, b0 = b0n, b1 = b1n, b2 = b2n, b3 = b3n;
    if (s < 7){
      afn = *(const short8v*)(arow + (s+1)*32);
      b0n = *(const short8v*)(wt0 + (s+1)*32);
      b1n = *(const short8v*)(wt0 + 16*4096 + (s+1)*32);
      b2n = *(const short8v*)(wt0 + 32*4096 + (s+1)*32);
      b3n = *(const short8v*)(wt0 + 48*4096 + (s+1)*32);
    }
    a0 = __builtin_amdgcn_mfma_f32_16x16x32_bf16(af, b0, a0, 0,0,0);
    a1 = __builtin_amdgcn_mfma_f32_16x16x32_bf16(af, b1, a1, 0,0,0);
    a2 = __builtin_amdgcn_mfma_f32_16x16x32_bf16(af, b2, a2, 0,0,0);
    a3 = __builtin_amdgcn_mfma_f32_16x16x32_bf16(af, b3, a3, 0,0,0);
  }
  #pragma unroll
  for (int r=0;r<4;r++){
    int q = qt*64 + w*16 + lg*4 + r;
    float* pp = partial + ((size_t)kh*8192 + q)*64;
    pp[l15]      = a0[r];
    pp[16 + l15] = a1[r];
    pp[32 + l15] = a2[r];
    pp[48 + l15] = a3[r];
  }
}

// ---------------- convep: sum 16 partials ----------------
__global__ __launch_bounds__(256) void k_convep(const float* __restrict__ partial,
    const float* __restrict__ xin, const float* __restrict__ dw, const float* __restrict__ db,
    const float* __restrict__ cb, float* __restrict__ xout){
  __shared__ float dws[4096];
  __shared__ float xs[4][64];
  int t = threadIdx.x;
  int co = t&63, qr = t>>6;
  int n = blockIdx.x*4 + qr;
  #pragma unroll
  for (int i=0;i<4;i++) ((float4*)dws)[i*256+t] = ((const float4*)dw)[i*256+t];
  xs[qr][co] = xin[(size_t)n*64+co];
  __syncthreads();
  float y = cb[co] + db[co];
  #pragma unroll
  for (int h=0;h<16;h++) y += partial[((size_t)h*8192 + n)*64 + co];
  for (int ci=0; ci<64; ci++) y += fmaxf(xs[qr][ci],0.f) * dws[ci*64+co];
  xout[(size_t)n*64+co] = y + xs[qr][co];
}

extern "C" void kernel_launch(void* const* d_in, const int* in_sizes, int n_in,
                              void* d_out, int out_size, void* d_ws, size_t ws_size,
                              hipStream_t stream) {
  const float* pos   = (const float*)d_in[0];
  const float* vel   = (const float*)d_in[1];
  const int*   fn    = (const int*)d_in[4];
  const float* cw0f  = (const float*)d_in[6];
  const float* cb0f  = (const float*)d_in[7];
  const float* cw1   = (const float*)d_in[10];
  const float* cb1   = (const float*)d_in[11];
  const float* cw2   = (const float*)d_in[12];
  const float* cb2   = (const float*)d_in[13];
  const float* cw3   = (const float*)d_in[14];
  const float* cb3   = (const float*)d_in[15];
  const float* dw1   = (const float*)d_in[16];
  const float* db1   = (const float*)d_in[17];
  const float* dw2   = (const float*)d_in[18];
  const float* db2   = (const float*)d_in[19];
  const float* dw3   = (const float*)d_in[20];
  const float* db3   = (const float*)d_in[21];
  const float* selfW = (const float*)d_in[22];
  const float* selfb = (const float*)d_in[23];
  const float* srcW  = (const float*)d_in[24];
  const float* srcb  = (const float*)d_in[25];
  const float* lna   = (const float*)d_in[26];
  const float* lnb   = (const float*)d_in[27];
  const float* ffw1  = (const float*)d_in[28];
  const float* ffb1  = (const float*)d_in[29];
  const float* ffw2  = (const float*)d_in[30];
  const float* ffb2  = (const float*)d_in[31];

  float* ws = (float*)d_ws;
  float* pos2   = ws + 0;
  float* feats4 = ws + 24576;
  float* a0f    = ws + 57344;
  unsigned short* Qb1 = (unsigned short*)(ws + 319488);
  unsigned short* Kb1 = (unsigned short*)(ws + 581632);
  unsigned short* VT1 = (unsigned short*)(ws + 843776);
  unsigned short* Q2b = (unsigned short*)(ws + 1105920);
  unsigned short* Kb2 = (unsigned short*)(ws + 1630208);
  unsigned short* VT2 = (unsigned short*)(ws + 1892352);
  float* Pacc   = ws + 2416640;
  float* Pml    = ws + 6610944;
  float* x0     = ws + 6873088;
  float* x1     = ws + 7397376;
  float* x2     = ws + 7921664;
  float4* geo   = (float4*)(ws + 8445952);
  unsigned short* WT1 = (unsigned short*)(ws + 9494528);
  unsigned short* WT2 = (unsigned short*)(ws + 9625600);
  unsigned short* Bg  = (unsigned short*)(ws + 9756672);
  float* partial = ws + 26533888;   // 16*8192*64 = 8.4M f32 -> ends 34922496

  float* outp = (float*)d_out;

  k_prepw<<<160, 256, 0, stream>>>(pos, vel, pos2, feats4, cw1, cw2, WT1, WT2);
  k_cconv0<<<NP/4, 256, 0, stream>>>(feats4, fn, pos2, geo, cw0f, cb0f, a0f);
  k_lnproj1<<<NP/4, 128, 0, stream>>>(a0f, lna, lnb, selfW, selfb, srcW, srcb, Qb1, Kb1, VT1, Q2b);
  k_attn_mfma<<<dim3(NP/64, 8), 256, 0, stream>>>(Qb1, Kb1, VT1, Pacc, Pml);
  k_merge1<<<NP/4, 128, 0, stream>>>(Pacc, Pml, a0f, selfW+3072, selfb+96, srcW, srcb, Kb2, VT2);
  k_attn_mfma<<<dim3(NP/64, 8), 256, 0, stream>>>(Q2b, Kb2, VT2, Pacc, Pml);
  k_merge2<<<NP/4, 128, 0, stream>>>(Pacc, Pml, a0f, srcW+3072, srcb+96, lna, lnb,
                                     ffw1, ffb1, ffw2, ffb2, x0);

  // layer 1
  k_build<<<NP/4, 256, 0, stream>>>(x0, fn, geo, Bg);
  k_gemmB<<<dim3(128,16), 256, 0, stream>>>(Bg, WT1, partial);
  k_convep<<<NP/4, 256, 0, stream>>>(partial, x0, dw1, db1, cb1, x1);
  // layer 2
  k_build<<<NP/4, 256, 0, stream>>>(x1, fn, geo, Bg);
  k_gemmB<<<dim3(128,16), 256, 0, stream>>>(Bg, WT2, partial);
  k_convep<<<NP/4, 256, 0, stream>>>(partial, x1, dw2, db2, cb2, x2);
  // final layer: fused, no Bg
  k_buildgemm3<<<NP/4, 256, 0, stream>>>(x2, fn, geo, cw3, cb3, dw3, db3, pos, pos2, outp);
}

// Round 25
// 262.686 us; speedup vs baseline: 1.0279x; 1.0279x over previous
//
#include <hip/hip_runtime.h>
#include <hip/hip_bf16.h>
#include <math.h>

#define NP 8192
#define KN 32

typedef __attribute__((ext_vector_type(8))) short short8v;   // 8 bf16
typedef __attribute__((ext_vector_type(4))) short short4v;   // 4 bf16
typedef __attribute__((ext_vector_type(4))) float f32x4v;
typedef __attribute__((ext_vector_type(16))) float f32x16v;

__device__ __forceinline__ float sgnf(float x){ return (x>0.f)?1.f:((x<0.f)?-1.f:0.f); }
__device__ __forceinline__ unsigned short f2bf(float f){
  unsigned u = __float_as_uint(f);
  unsigned r = (u + 0x7FFFu + ((u>>16)&1u)) >> 16;
  return (unsigned short)r;
}
__device__ __forceinline__ unsigned short f2bf_n(float f){
  __hip_bfloat16 h = __float2bfloat16(f);
  return reinterpret_cast<unsigned short&>(h);
}
__device__ __forceinline__ float bf2f(unsigned short u){ return __uint_as_float(((unsigned)u)<<16); }

// compute compressed geometry {w, tx, ty, tz} for (query n, neighbor nb)
__device__ __forceinline__ float4 geo_compute(const float* __restrict__ pos2, int n, int nb){
  const float R = 0.5f * (float)(1.5*6.0*0.025);
  float x = (pos2[nb*3+0]-pos2[n*3+0])/R;
  float y = (pos2[nb*3+1]-pos2[n*3+1])/R;
  float z = (pos2[nb*3+2]-pos2[n*3+2])/R;
  float sq = x*x+y*y+z*z;
  float wgt = 0.f;
  if (sq < 1.f){ float t1 = 1.f-sq; wgt = t1*t1*t1; }
  if (nb == n) wgt = 0.f;
  const float eps = 1e-8f;
  float norm = sqrtf(sq);
  float sq_xy = x*x+y*y;
  bool polar = 1.25f*z*z > sq_xy;
  float sa = sqrtf(3.f*norm/(norm+fabsf(z)+eps));
  float sb = norm/(sqrtf(sq_xy)+eps);
  float xc = polar ? x*sa : x*sb;
  float yc = polar ? y*sa : y*sb;
  float zc = polar ? sgnf(z)*norm : 1.5f*z;
  if (sq < eps){ xc=x; yc=y; zc=z; }
  float nxy = sqrtf(xc*xc+yc*yc);
  const float fo_pi = (float)(4.0/3.141592653589793);
  float sx = (fabsf(xc)>eps) ? xc : eps;
  float sy = (fabsf(yc)>eps) ? yc : eps;
  float ux = sgnf(xc)*nxy;
  float vv = sgnf(yc)*nxy;
  bool xbig = fabsf(yc) <= fabsf(xc);
  float u = xbig ? ux : vv*fo_pi*atanf(xc/sy);
  float v = xbig ? ux*fo_pi*atanf(yc/sx) : vv;
  if (nxy < eps){ u = xc; v = yc; }
  float tx = fminf(fmaxf((u  + 1.f)*1.5f, 0.f), 3.f);
  float ty = fminf(fmaxf((v  + 1.f)*1.5f, 0.f), 3.f);
  float tz = fminf(fmaxf((zc + 1.f)*1.5f, 0.f), 3.f);
  return make_float4(wgt, tx, ty, tz);
}

__device__ __forceinline__ void corners_from_geo(float4 g, float* gg, int* bb){
  float tx=g.y, ty=g.z, tz=g.w, w=g.x;
  int ix = (int)floorf(tx); ix = ix>2?2:ix;
  int iy = (int)floorf(ty); iy = iy>2?2:iy;
  int iz = (int)floorf(tz); iz = iz>2?2:iz;
  float fx = tx-(float)ix, fy = ty-(float)iy, fz = tz-(float)iz;
  float wxa[2] = {1.f-fx, fx};
  float wya[2] = {1.f-fy, fy};
  float wza[2] = {1.f-fz, fz};
  int b000 = ix*16 + iy*4 + iz;
  #pragma unroll
  for (int cc=0; cc<8; cc++){
    int cx = cc>>2, cy = (cc>>1)&1, cz = cc&1;
    gg[cc] = w * wxa[cx]*wya[cy]*wza[cz];
    bb[cc] = b000 + cx*16 + cy*4 + cz;
  }
}

// ---------------- prep + weight transpose fused ----------------
__global__ __launch_bounds__(256) void k_prepw(const float* __restrict__ pos, const float* __restrict__ vel,
    float* __restrict__ pos2, float* __restrict__ feats4,
    const float* __restrict__ W1, const float* __restrict__ W2,
    unsigned short* __restrict__ WT1, unsigned short* __restrict__ WT2){
  __shared__ unsigned short tile[64][72];
  int t = threadIdx.x;
  if (blockIdx.x < 32){
    int i = blockIdx.x*256 + t;
    const float DT = 0.02f;
    float vx = vel[i*3+0], vy = vel[i*3+1], vz = vel[i*3+2];
    float v2x = vx;
    float v2y = vy + DT*(-9.81f);
    float v2z = vz;
    float px = pos[i*3+0] + (DT*(v2x+vx))*0.5f;
    float py = pos[i*3+1] + (DT*(v2y+vy))*0.5f;
    float pz = pos[i*3+2] + (DT*(v2z+vz))*0.5f;
    pos2[i*3+0]=px; pos2[i*3+1]=py; pos2[i*3+2]=pz;
    feats4[i*4+0]=1.f; feats4[i*4+1]=v2x; feats4[i*4+2]=v2y; feats4[i*4+3]=v2z;
    return;
  }
  int b2 = blockIdx.x - 32;
  const float* W = (b2 < 64) ? W1 : W2;
  unsigned short* WT = (b2 < 64) ? WT1 : WT2;
  int kb = (b2 & 63)*64;
  {
    int co = t&63, kr = t>>6;
    #pragma unroll
    for (int i=0;i<16;i++){
      int k = i*4 + kr;
      tile[co][k] = f2bf(W[(size_t)(kb+k)*64 + co]);
    }
  }
  __syncthreads();
  {
    int kk = t&63, cor = t>>6;
    #pragma unroll
    for (int i=0;i<16;i++){
      int co2 = i*4 + cor;
      WT[(size_t)co2*4096 + kb + kk] = tile[co2][kk];
    }
  }
}

// ---------------- cconv0 + fused geometry ----------------
__global__ __launch_bounds__(256) void k_cconv0(const float* __restrict__ feats4, const int* __restrict__ nbrs,
    const float* __restrict__ pos2, float4* __restrict__ geo,
    const float* __restrict__ W0, const float* __restrict__ b0, float* __restrict__ a0f){
  __shared__ float CWT[4][64][33];
  __shared__ float Xs[4][32][4];
  __shared__ float Ws[8192];
  __shared__ float Bl[4][320];
  int t = threadIdx.x, lane = t&63, w = t>>6;
  int n = blockIdx.x*4 + w;
  #pragma unroll
  for (int i=0;i<32;i++) Ws[i*256+t] = W0[i*256+t];
  {
    float* cw = &CWT[w][0][0];
    #pragma unroll
    for (int i=0;i<33;i++) cw[i*64+lane] = 0.f;
  }
  if (lane < 32){
    int idx = n*KN + lane;
    int nb = nbrs[idx];
    *(float4*)&Xs[w][lane][0] = *(const float4*)(feats4 + (size_t)nb*4);
    float4 g = geo_compute(pos2, n, nb);
    geo[idx] = g;
    float gg[8]; int bb[8];
    corners_from_geo(g, gg, bb);
    __builtin_amdgcn_s_waitcnt(0);
    #pragma unroll
    for (int cc=0;cc<8;cc++) CWT[w][bb[cc]][lane] = gg[cc];
  }
  __syncthreads();
  float bacc0=0.f, bacc1=0.f, bacc2=0.f, bacc3=0.f;
  #pragma unroll 8
  for (int k=0;k<32;k++){
    float cw = CWT[w][lane][k];
    float4 xk = *(float4*)&Xs[w][k][0];
    bacc0 += cw*xk.x; bacc1 += cw*xk.y; bacc2 += cw*xk.z; bacc3 += cw*xk.w;
  }
  Bl[w][lane*5+0]=bacc0; Bl[w][lane*5+1]=bacc1; Bl[w][lane*5+2]=bacc2; Bl[w][lane*5+3]=bacc3;
  __syncthreads();
  {
    int h = lane>>5, co = lane&31;
    float acc = h ? 0.f : b0[co];
    int k0 = h*128;
    #pragma unroll 8
    for (int kk=0;kk<128;kk++){
      int kx = k0+kk;
      acc += Bl[w][(kx>>2)*5 + (kx&3)] * Ws[kx*32+co];
    }
    acc += __shfl_xor(acc, 32);
    if (h == 0) a0f[(size_t)n*32+co] = acc;
  }
}

// ---------------- LN(a0f) twice + bf16 Q1(scaled),K1,V1^T + Q2(scaled) ----------------
__global__ __launch_bounds__(128) void k_lnproj1(const float* __restrict__ a0f,
    const float* __restrict__ lna, const float* __restrict__ lnb,
    const float* __restrict__ selfW, const float* __restrict__ selfb,
    const float* __restrict__ srcW, const float* __restrict__ srcb,
    unsigned short* __restrict__ Qb1, unsigned short* __restrict__ Kb1,
    unsigned short* __restrict__ VT1, unsigned short* __restrict__ Q2b){
  __shared__ float sh[4][2][32];
  int t=threadIdx.x, rr=t>>5, c=t&31;
  int r = blockIdx.x*4+rr;
  float x = a0f[r*32+c];
  float s = x;
  for (int o=16;o;o>>=1) s += __shfl_xor(s,o,32);
  float mu = s*(1.f/32.f);
  float d = x-mu;
  float s2 = d*d;
  for (int o=16;o;o>>=1) s2 += __shfl_xor(s2,o,32);
  float istd = 1.f/(sqrtf(s2*(1.f/31.f))+1e-6f);
  sh[rr][0][c] = lna[c]*d*istd + lnb[c];
  sh[rr][1][c] = lna[32+c]*d*istd + lnb[32+c];
  __syncthreads();
  float aq = selfb[c], ak = selfb[32+c], av = selfb[64+c], aq2 = srcb[c];
  for (int cc=0;cc<32;cc++){
    float v0 = sh[rr][0][cc], v1 = sh[rr][1][cc];
    aq  += v0*selfW[cc*32+c];
    ak  += v0*selfW[1024+cc*32+c];
    av  += v0*selfW[2048+cc*32+c];
    aq2 += v1*srcW[cc*32+c];
  }
  const float scl = 0.17677669529663687f;
  Qb1[r*32+c] = f2bf(aq*scl);
  Kb1[r*32+c] = f2bf(ak);
  VT1[(size_t)c*8192 + r] = f2bf(av);
  Q2b[r*32+c] = f2bf(aq2*scl);
}

// ---------------- MFMA flash-attention: 64-key staged tiles, fixed-ref softmax, 8 partitions ----------------
__global__ __launch_bounds__(256) void k_attn_mfma(const unsigned short* __restrict__ Qb,
    const unsigned short* __restrict__ Kb, const unsigned short* __restrict__ VT,
    float* __restrict__ Pacc, float* __restrict__ Pml){
  __shared__ unsigned short Ks[2][64][40];
  __shared__ unsigned short Vs[2][32][72];
  __shared__ float Ot[4][16][36];
  int t = threadIdx.x, lane = t&63, w = t>>6;
  int qb = blockIdx.x, kp = blockIdx.y;
  int q0 = qb*64 + w*16;
  int l15 = lane&15, lg = lane>>4;
  short8v qf = *(const short8v*)(Qb + (size_t)(q0+l15)*32 + lg*8);
  f32x4v o0 = {0.f,0.f,0.f,0.f}, o1 = {0.f,0.f,0.f,0.f};
  f32x4v cz = {0.f,0.f,0.f,0.f};
  const float M0 = 8.f;
  float lacc = 0.f;
  int kbase = kp*1024;

#define STAGE(KT, BUF) do {                                                     \
    int _kb = kbase + (KT)*64;                                                  \
    if (t < 128){                                                               \
      int _row = t>>1, _seg = t&1;                                              \
      const unsigned short* _src = Kb + (size_t)(_kb+_row)*32 + _seg*16;        \
      uint4 _u0 = *(const uint4*)_src;                                          \
      uint4 _u1 = *(const uint4*)(_src+8);                                      \
      *(uint4*)&Ks[BUF][_row][_seg*16]   = _u0;                                 \
      *(uint4*)&Ks[BUF][_row][_seg*16+8] = _u1;                                 \
    } else {                                                                    \
      int _tt = t-128; int _dim = _tt>>2, _seg = _tt&3;                         \
      const unsigned short* _src = VT + (size_t)_dim*8192 + _kb + _seg*16;      \
      uint4 _u0 = *(const uint4*)_src;                                          \
      uint4 _u1 = *(const uint4*)(_src+8);                                      \
      *(uint4*)&Vs[BUF][_dim][_seg*16]   = _u0;                                 \
      *(uint4*)&Vs[BUF][_dim][_seg*16+8] = _u1;                                 \
    }                                                                           \
  } while(0)

  STAGE(0, 0);
  __syncthreads();
  for (int kt=0; kt<16; kt++){
    int b = kt&1;
    if (kt < 15) STAGE(kt+1, b^1);
    #pragma unroll
    for (int h=0; h<2; h++){
      int kk = h*32;
      short8v kf0 = *(const short8v*)&Ks[b][kk+l15][lg*8];
      short8v kf1 = *(const short8v*)&Ks[b][kk+16+l15][lg*8];
      short4v v0a = *(const short4v*)&Vs[b][l15][kk+lg*4];
      short4v v0b = *(const short4v*)&Vs[b][l15][kk+16+lg*4];
      short4v v1a = *(const short4v*)&Vs[b][16+l15][kk+lg*4];
      short4v v1b = *(const short4v*)&Vs[b][16+l15][kk+16+lg*4];
      f32x4v sa = __builtin_amdgcn_mfma_f32_16x16x32_bf16(kf0, qf, cz, 0,0,0);
      f32x4v sb = __builtin_amdgcn_mfma_f32_16x16x32_bf16(kf1, qf, cz, 0,0,0);
      float p0 = __expf(fminf(sa[0]-M0, 30.f)), p1 = __expf(fminf(sa[1]-M0, 30.f));
      float p2 = __expf(fminf(sa[2]-M0, 30.f)), p3 = __expf(fminf(sa[3]-M0, 30.f));
      float p4 = __expf(fminf(sb[0]-M0, 30.f)), p5 = __expf(fminf(sb[1]-M0, 30.f));
      float p6 = __expf(fminf(sb[2]-M0, 30.f)), p7 = __expf(fminf(sb[3]-M0, 30.f));
      lacc += (p0+p1)+(p2+p3)+(p4+p5)+(p6+p7);
      ushort4 ppa, ppb;
      ppa.x = f2bf_n(p0); ppa.y = f2bf_n(p1); ppa.z = f2bf_n(p2); ppa.w = f2bf_n(p3);
      ppb.x = f2bf_n(p4); ppb.y = f2bf_n(p5); ppb.z = f2bf_n(p6); ppb.w = f2bf_n(p7);
      short4v pfa = *(short4v*)&ppa;
      short4v pfb = *(short4v*)&ppb;
      o0 = __builtin_amdgcn_mfma_f32_16x16x16bf16_1k(v0a, pfa, o0, 0,0,0);
      o0 = __builtin_amdgcn_mfma_f32_16x16x16bf16_1k(v0b, pfb, o0, 0,0,0);
      o1 = __builtin_amdgcn_mfma_f32_16x16x16bf16_1k(v1a, pfa, o1, 0,0,0);
      o1 = __builtin_amdgcn_mfma_f32_16x16x16bf16_1k(v1b, pfb, o1, 0,0,0);
    }
    __syncthreads();
  }
#undef STAGE
  lacc += __shfl_xor(lacc, 16);
  lacc += __shfl_xor(lacc, 32);
  #pragma unroll
  for (int r=0;r<4;r++){
    Ot[w][l15][lg*4+r] = o0[r];
    Ot[w][l15][16+lg*4+r] = o1[r];
  }
  __builtin_amdgcn_s_waitcnt(0);
  {
    size_t pi = ((size_t)(q0+l15)*8 + kp)*32;
    float4 a = *(float4*)&Ot[w][l15][lg*8];
    float4 b = *(float4*)&Ot[w][l15][lg*8+4];
    *(float4*)(Pacc + pi + lg*8)     = a;
    *(float4*)(Pacc + pi + lg*8 + 4) = b;
    if (lg == 0){
      Pml[((size_t)(q0+l15)*8 + kp)*2 + 0] = M0;
      Pml[((size_t)(q0+l15)*8 + kp)*2 + 1] = lacc;
    }
  }
}

// ---------------- merge1 ----------------
__global__ __launch_bounds__(128) void k_merge1(const float* __restrict__ Pacc, const float* __restrict__ Pml,
    const float* __restrict__ resid, const float* __restrict__ Wo, const float* __restrict__ bo,
    const float* __restrict__ srcW, const float* __restrict__ srcb,
    unsigned short* __restrict__ Kb2, unsigned short* __restrict__ VT2){
  __shared__ float sh[4][32];
  __shared__ float shh[4][32];
  int t=threadIdx.x, rr=t>>5, c=t&31;
  int r = blockIdx.x*4+rr;
  float m = -1e30f;
  for (int p=0;p<8;p++) m = fmaxf(m, Pml[(r*8+p)*2]);
  float l = 0.f, a = 0.f;
  for (int p=0;p<8;p++){
    float mp = Pml[(r*8+p)*2], lp = Pml[(r*8+p)*2+1];
    float sc = expf(mp-m);
    l += lp*sc;
    a += Pacc[(r*8+p)*32+c]*sc;
  }
  sh[rr][c] = a/l;
  __syncthreads();
  float acc = bo[c];
  for (int cc=0;cc<32;cc++) acc += sh[rr][cc]*Wo[cc*32+c];
  float h = resid[r*32+c] + acc;
  shh[rr][c] = h;
  __syncthreads();
  float ak = srcb[32+c], av = srcb[64+c];
  for (int cc=0;cc<32;cc++){
    float v = shh[rr][cc];
    ak += v*srcW[1024+cc*32+c];
    av += v*srcW[2048+cc*32+c];
  }
  Kb2[r*32+c] = f2bf(ak);
  VT2[(size_t)c*8192 + r] = f2bf(av);
}

// ---------------- merge2 ----------------
__global__ __launch_bounds__(128) void k_merge2(const float* __restrict__ Pacc, const float* __restrict__ Pml,
    const float* __restrict__ resid, const float* __restrict__ Wo, const float* __restrict__ bo,
    const float* __restrict__ lna, const float* __restrict__ lnb,
    const float* __restrict__ w1, const float* __restrict__ b1,
    const float* __restrict__ w2, const float* __restrict__ b2, float* __restrict__ x0){
  __shared__ float sh[4][32];
  __shared__ float sh2[4][64];
  int t=threadIdx.x, rr=t>>5, c=t&31;
  int r = blockIdx.x*4+rr;
  float m = -1e30f;
  for (int p=0;p<8;p++) m = fmaxf(m, Pml[(r*8+p)*2]);
  float l = 0.f, a = 0.f;
  for (int p=0;p<8;p++){
    float mp = Pml[(r*8+p)*2], lp = Pml[(r*8+p)*2+1];
    float sc = expf(mp-m);
    l += lp*sc;
    a += Pacc[(r*8+p)*32+c]*sc;
  }
  sh[rr][c] = a/l;
  __syncthreads();
  float acc = bo[c];
  for (int cc=0;cc<32;cc++) acc += sh[rr][cc]*Wo[cc*32+c];
  float x = resid[r*32+c] + acc;      // h2
  __syncthreads();
  float s = x;
  for (int o=16;o;o>>=1) s += __shfl_xor(s,o,32);
  float mu = s*(1.f/32.f);
  float d = x-mu;
  float s2 = d*d;
  for (int o=16;o;o>>=1) s2 += __shfl_xor(s2,o,32);
  float istd = 1.f/(sqrtf(s2*(1.f/31.f))+1e-6f);
  sh[rr][c] = lna[64+c]*d*istd + lnb[64+c];
  __syncthreads();
  #pragma unroll
  for (int jj=0;jj<2;jj++){
    int j = c + jj*32;
    float h = b1[j];
    for (int cc=0;cc<32;cc++) h += sh[rr][cc]*w1[cc*64+j];
    sh2[rr][j] = fmaxf(h, 0.f);
  }
  __syncthreads();
  #pragma unroll
  for (int jj=0;jj<2;jj++){
    int j = c + jj*32;
    float o = b2[j];
    for (int kk=0;kk<64;kk++) o += sh2[rr][kk]*w2[kk*64+j];
    x0[r*64+j] = o;
  }
}

// ---------------- build B via MFMA (atomic-free), full NP ----------------
__global__ __launch_bounds__(256) void k_build(const float* __restrict__ xin, const int* __restrict__ nbrs,
    const float4* __restrict__ geo, unsigned short* __restrict__ Bg){
  __shared__ unsigned short XT[4][2560];
  __shared__ unsigned short CWT[4][2560];
  int t = threadIdx.x, lane = t&63, w = t>>6;
  int n = blockIdx.x*4 + w;
  unsigned short* xt = XT[w];
  unsigned short* cwt = CWT[w];
  #pragma unroll
  for (int i=0;i<5;i++) ((uint4*)cwt)[i*64+lane] = make_uint4(0u,0u,0u,0u);
  int nreg = 0; float4 g = make_float4(0.f,0.f,0.f,0.f);
  if (lane < 32){
    nreg = nbrs[n*KN + lane];
    g = geo[(size_t)n*KN + lane];
  }
  float xv[32];
  #pragma unroll
  for (int k=0;k<32;k++){
    int nb = __shfl(nreg, k);
    xv[k] = xin[(size_t)nb*64 + lane];
  }
  #pragma unroll
  for (int k2=0;k2<16;k2++){
    unsigned lo = f2bf(fmaxf(xv[2*k2],   0.f));
    unsigned hi = f2bf(fmaxf(xv[2*k2+1], 0.f));
    *(unsigned*)&xt[lane*40 + 2*k2] = lo | (hi<<16);
  }
  if (lane < 32){
    float gg[8]; int bb[8];
    corners_from_geo(g, gg, bb);
    #pragma unroll
    for (int cc=0;cc<8;cc++) cwt[bb[cc]*40 + lane] = f2bf(gg[cc]);
  }
  int l31 = lane&31, lg = lane>>5;
  short8v af[2][2], bf[2][2];
  #pragma unroll
  for (int bt=0;bt<2;bt++)
    #pragma unroll
    for (int kc=0;kc<2;kc++)
      af[bt][kc] = *(short8v*)&cwt[(bt*32+l31)*40 + kc*16 + lg*8];
  #pragma unroll
  for (int ct=0;ct<2;ct++)
    #pragma unroll
    for (int kc=0;kc<2;kc++)
      bf[ct][kc] = *(short8v*)&xt[(ct*32+l31)*40 + kc*16 + lg*8];
  f32x16v acc[2][2];
  #pragma unroll
  for (int bt=0;bt<2;bt++)
    #pragma unroll
    for (int ct=0;ct<2;ct++){
      f32x16v z = {0.f,0.f,0.f,0.f,0.f,0.f,0.f,0.f,0.f,0.f,0.f,0.f,0.f,0.f,0.f,0.f};
      z = __builtin_amdgcn_mfma_f32_32x32x16_bf16(af[bt][0], bf[ct][0], z, 0,0,0);
      z = __builtin_amdgcn_mfma_f32_32x32x16_bf16(af[bt][1], bf[ct][1], z, 0,0,0);
      acc[bt][ct] = z;
    }
  unsigned short* dst = Bg + (size_t)n*4096;
  #pragma unroll
  for (int bt=0;bt<2;bt++)
    #pragma unroll
    for (int ct=0;ct<2;ct++)
      #pragma unroll
      for (int r=0;r<16;r++){
        int row = (r&3) + 8*(r>>2) + 4*lg;
        dst[(bt*32+row)*64 + ct*32 + l31] = f2bf(acc[bt][ct][r]);
      }
}

// ---------------- fused build + gemm3 + epilogue ----------------
__global__ __launch_bounds__(256) void k_buildgemm3(const float* __restrict__ xin, const int* __restrict__ nbrs,
    const float4* __restrict__ geo, const float* __restrict__ W3,
    const float* __restrict__ cb3, const float* __restrict__ dw3, const float* __restrict__ db3,
    const float* __restrict__ pos, const float* __restrict__ pos2, float* __restrict__ outp){
  __shared__ unsigned short XT[4][2560];
  __shared__ unsigned short CWT[4][2560];
  __shared__ unsigned short W3p[3][4096];
  int t = threadIdx.x, lane = t&63, w = t>>6;
  int n = blockIdx.x*4 + w;
  unsigned short* xt  = XT[w];
  unsigned short* cwt = CWT[w];
  #pragma unroll
  for (int co=0; co<3; co++)
    #pragma unroll
    for (int i=0;i<16;i++){
      int k = t + i*256;
      W3p[co][k] = f2bf(W3[(size_t)k*3 + co]);
    }
  #pragma unroll
  for (int i=0;i<5;i++) ((uint4*)cwt)[i*64+lane] = make_uint4(0u,0u,0u,0u);
  int nreg = 0; float4 g = make_float4(0.f,0.f,0.f,0.f);
  if (lane < 32){
    nreg = nbrs[n*KN + lane];
    g = geo[(size_t)n*KN + lane];
  }
  float xv[32];
  #pragma unroll
  for (int k=0;k<32;k++){
    int nb = __shfl(nreg, k);
    xv[k] = xin[(size_t)nb*64 + lane];
  }
  float xq = fmaxf(xin[(size_t)n*64 + lane], 0.f);
  float3 dwv;
  dwv.x = dw3[lane*3+0]; dwv.y = dw3[lane*3+1]; dwv.z = dw3[lane*3+2];
  #pragma unroll
  for (int k2=0;k2<16;k2++){
    unsigned lo = f2bf(fmaxf(xv[2*k2],   0.f));
    unsigned hi = f2bf(fmaxf(xv[2*k2+1], 0.f));
    *(unsigned*)&xt[lane*40 + 2*k2] = lo | (hi<<16);
  }
  if (lane < 32){
    float gg[8]; int bb[8];
    corners_from_geo(g, gg, bb);
    #pragma unroll
    for (int cc=0;cc<8;cc++) cwt[bb[cc]*40 + lane] = f2bf(gg[cc]);
  }
  __syncthreads();
  int l31 = lane&31, lg = lane>>5;
  short8v af[2][2], bf[2][2];
  #pragma unroll
  for (int bt=0;bt<2;bt++)
    #pragma unroll
    for (int kc=0;kc<2;kc++)
      af[bt][kc] = *(short8v*)&cwt[(bt*32+l31)*40 + kc*16 + lg*8];
  #pragma unroll
  for (int ct=0;ct<2;ct++)
    #pragma unroll
    for (int kc=0;kc<2;kc++)
      bf[ct][kc] = *(short8v*)&xt[(ct*32+l31)*40 + kc*16 + lg*8];
  f32x16v acc[2][2];
  #pragma unroll
  for (int bt=0;bt<2;bt++)
    #pragma unroll
    for (int ct=0;ct<2;ct++){
      f32x16v z = {0.f,0.f,0.f,0.f,0.f,0.f,0.f,0.f,0.f,0.f,0.f,0.f,0.f,0.f,0.f,0.f};
      z = __builtin_amdgcn_mfma_f32_32x32x16_bf16(af[bt][0], bf[ct][0], z, 0,0,0);
      z = __builtin_amdgcn_mfma_f32_32x32x16_bf16(af[bt][1], bf[ct][1], z, 0,0,0);
      acc[bt][ct] = z;
    }
  float y0 = xq*dwv.x, y1 = xq*dwv.y, y2 = xq*dwv.z;
  #pragma unroll
  for (int bt=0;bt<2;bt++)
    #pragma unroll
    for (int ct=0;ct<2;ct++)
      #pragma unroll
      for (int r=0;r<16;r++){
        int row = (r&3) + 8*(r>>2) + 4*lg;
        int k = (bt*32+row)*64 + ct*32 + l31;
        float b = bf2f(f2bf(acc[bt][ct][r]));
        y0 += b * bf2f(W3p[0][k]);
        y1 += b * bf2f(W3p[1][k]);
        y2 += b * bf2f(W3p[2][k]);
      }
  #pragma unroll
  for (int m=1; m<64; m<<=1){
    y0 += __shfl_xor(y0, m);
    y1 += __shfl_xor(y1, m);
    y2 += __shfl_xor(y2, m);
  }
  if (lane < 3){
    int co = lane;
    float y = (co==0 ? y0 : (co==1 ? y1 : y2)) + cb3[co] + db3[co];
    float pc = y*(1.f/128.f);
    float po = pos2[n*3+co] + pc;
    outp[n*3+co] = po;
    outp[NP*3 + n*3+co] = (po - pos[n*3+co]) / 0.02f;
  }
}

// ---------------- gemmB: K-split 8 (16 MFMA steps/wave), 2-deep pipeline ----------------
__global__ __launch_bounds__(256, 4) void k_gemmB(const unsigned short* __restrict__ Bg,
    const unsigned short* __restrict__ WT, float* __restrict__ partial){
  int t = threadIdx.x, lane = t&63, w = t>>6;
  int qt = blockIdx.x, kh = blockIdx.y;
  int l15 = lane&15, lg = lane>>4;
  int kbase = kh*512;
  const unsigned short* arow = Bg + (size_t)(qt*64 + w*16 + l15)*4096 + kbase + lg*8;
  const unsigned short* wt0 = WT + (size_t)l15*4096 + kbase + lg*8;
  f32x4v a0 = {0.f,0.f,0.f,0.f}, a1 = {0.f,0.f,0.f,0.f};
  f32x4v a2 = {0.f,0.f,0.f,0.f}, a3 = {0.f,0.f,0.f,0.f};
  short8v afn = *(const short8v*)(arow);
  short8v b0n = *(const short8v*)(wt0);
  short8v b1n = *(const short8v*)(wt0 + 16*4096);
  short8v b2n = *(const short8v*)(wt0 + 32*4096);
  short8v b3n = *(const short8v*)(wt0 + 48*4096);
  #pragma unroll
  for (int s=0;s<16;s++){
    short8v af = afn, b0 = b0n, b1 = b1n, b2 = b2n, b3 = b3n;
    if (s < 15){
      afn = *(const short8v*)(arow + (s+1)*32);
      b0n = *(const short8v*)(wt0 + (s+1)*32);
      b1n = *(const short8v*)(wt0 + 16*4096 + (s+1)*32);
      b2n = *(const short8v*)(wt0 + 32*4096 + (s+1)*32);
      b3n = *(const short8v*)(wt0 + 48*4096 + (s+1)*32);
    }
    a0 = __builtin_amdgcn_mfma_f32_16x16x32_bf16(af, b0, a0, 0,0,0);
    a1 = __builtin_amdgcn_mfma_f32_16x16x32_bf16(af, b1, a1, 0,0,0);
    a2 = __builtin_amdgcn_mfma_f32_16x16x32_bf16(af, b2, a2, 0,0,0);
    a3 = __builtin_amdgcn_mfma_f32_16x16x32_bf16(af, b3, a3, 0,0,0);
  }
  #pragma unroll
  for (int r=0;r<4;r++){
    int q = qt*64 + w*16 + lg*4 + r;
    float* pp = partial + ((size_t)kh*8192 + q)*64;
    pp[l15]      = a0[r];
    pp[16 + l15] = a1[r];
    pp[32 + l15] = a2[r];
    pp[48 + l15] = a3[r];
  }
}

// ---------------- convep: sum 8 partials ----------------
__global__ __launch_bounds__(256) void k_convep(const float* __restrict__ partial,
    const float* __restrict__ xin, const float* __restrict__ dw, const float* __restrict__ db,
    const float* __restrict__ cb, float* __restrict__ xout){
  __shared__ float dws[4096];
  __shared__ float xs[4][64];
  int t = threadIdx.x;
  int co = t&63, qr = t>>6;
  int n = blockIdx.x*4 + qr;
  #pragma unroll
  for (int i=0;i<4;i++) ((float4*)dws)[i*256+t] = ((const float4*)dw)[i*256+t];
  xs[qr][co] = xin[(size_t)n*64+co];
  __syncthreads();
  float y = cb[co] + db[co];
  #pragma unroll
  for (int h=0;h<8;h++) y += partial[((size_t)h*8192 + n)*64 + co];
  for (int ci=0; ci<64; ci++) y += fmaxf(xs[qr][ci],0.f) * dws[ci*64+co];
  xout[(size_t)n*64+co] = y + xs[qr][co];
}

extern "C" void kernel_launch(void* const* d_in, const int* in_sizes, int n_in,
                              void* d_out, int out_size, void* d_ws, size_t ws_size,
                              hipStream_t stream) {
  const float* pos   = (const float*)d_in[0];
  const float* vel   = (const float*)d_in[1];
  const int*   fn    = (const int*)d_in[4];
  const float* cw0f  = (const float*)d_in[6];
  const float* cb0f  = (const float*)d_in[7];
  const float* cw1   = (const float*)d_in[10];
  const float* cb1   = (const float*)d_in[11];
  const float* cw2   = (const float*)d_in[12];
  const float* cb2   = (const float*)d_in[13];
  const float* cw3   = (const float*)d_in[14];
  const float* cb3   = (const float*)d_in[15];
  const float* dw1   = (const float*)d_in[16];
  const float* db1   = (const float*)d_in[17];
  const float* dw2   = (const float*)d_in[18];
  const float* db2   = (const float*)d_in[19];
  const float* dw3   = (const float*)d_in[20];
  const float* db3   = (const float*)d_in[21];
  const float* selfW = (const float*)d_in[22];
  const float* selfb = (const float*)d_in[23];
  const float* srcW  = (const float*)d_in[24];
  const float* srcb  = (const float*)d_in[25];
  const float* lna   = (const float*)d_in[26];
  const float* lnb   = (const float*)d_in[27];
  const float* ffw1  = (const float*)d_in[28];
  const float* ffb1  = (const float*)d_in[29];
  const float* ffw2  = (const float*)d_in[30];
  const float* ffb2  = (const float*)d_in[31];

  float* ws = (float*)d_ws;
  float* pos2   = ws + 0;
  float* feats4 = ws + 24576;
  float* a0f    = ws + 57344;
  unsigned short* Qb1 = (unsigned short*)(ws + 319488);
  unsigned short* Kb1 = (unsigned short*)(ws + 581632);
  unsigned short* VT1 = (unsigned short*)(ws + 843776);
  unsigned short* Q2b = (unsigned short*)(ws + 1105920);
  unsigned short* Kb2 = (unsigned short*)(ws + 1630208);
  unsigned short* VT2 = (unsigned short*)(ws + 1892352);
  float* Pacc   = ws + 2416640;
  float* Pml    = ws + 6610944;
  float* x0     = ws + 6873088;
  float* x1     = ws + 7397376;
  float* x2     = ws + 7921664;
  float4* geo   = (float4*)(ws + 8445952);
  unsigned short* WT1 = (unsigned short*)(ws + 9494528);
  unsigned short* WT2 = (unsigned short*)(ws + 9625600);
  unsigned short* Bg  = (unsigned short*)(ws + 9756672);
  float* partial = ws + 26533888;

  float* outp = (float*)d_out;

  k_prepw<<<160, 256, 0, stream>>>(pos, vel, pos2, feats4, cw1, cw2, WT1, WT2);
  k_cconv0<<<NP/4, 256, 0, stream>>>(feats4, fn, pos2, geo, cw0f, cb0f, a0f);
  k_lnproj1<<<NP/4, 128, 0, stream>>>(a0f, lna, lnb, selfW, selfb, srcW, srcb, Qb1, Kb1, VT1, Q2b);
  k_attn_mfma<<<dim3(NP/64, 8), 256, 0, stream>>>(Qb1, Kb1, VT1, Pacc, Pml);
  k_merge1<<<NP/4, 128, 0, stream>>>(Pacc, Pml, a0f, selfW+3072, selfb+96, srcW, srcb, Kb2, VT2);
  k_attn_mfma<<<dim3(NP/64, 8), 256, 0, stream>>>(Q2b, Kb2, VT2, Pacc, Pml);
  k_merge2<<<NP/4, 128, 0, stream>>>(Pacc, Pml, a0f, srcW+3072, srcb+96, lna, lnb,
                                     ffw1, ffb1, ffw2, ffb2, x0);

  // layer 1
  k_build<<<NP/4, 256, 0, stream>>>(x0, fn, geo, Bg);
  k_gemmB<<<dim3(128,8), 256, 0, stream>>>(Bg, WT1, partial);
  k_convep<<<NP/4, 256, 0, stream>>>(partial, x0, dw1, db1, cb1, x1);
  // layer 2
  k_build<<<NP/4, 256, 0, stream>>>(x1, fn, geo, Bg);
  k_gemmB<<<dim3(128,8), 256, 0, stream>>>(Bg, WT2, partial);
  k_convep<<<NP/4, 256, 0, stream>>>(partial, x1, dw2, db2, cb2, x2);
  // final layer: fused, no Bg
  k_buildgemm3<<<NP/4, 256, 0, stream>>>(x2, fn, geo, cw3, cb3, dw3, db3, pos, pos2, outp);
}

// Round 26
// 220.801 us; speedup vs baseline: 1.2229x; 1.1897x over previous
//
#include <hip/hip_runtime.h>
#include <hip/hip_bf16.h>
#include <math.h>

#define NP 8192
#define KN 32

typedef __attribute__((ext_vector_type(8))) short short8v;   // 8 bf16
typedef __attribute__((ext_vector_type(4))) short short4v;   // 4 bf16
typedef __attribute__((ext_vector_type(4))) float f32x4v;
typedef __attribute__((ext_vector_type(16))) float f32x16v;

__device__ __forceinline__ float sgnf(float x){ return (x>0.f)?1.f:((x<0.f)?-1.f:0.f); }
__device__ __forceinline__ unsigned short f2bf(float f){
  unsigned u = __float_as_uint(f);
  unsigned r = (u + 0x7FFFu + ((u>>16)&1u)) >> 16;
  return (unsigned short)r;
}
__device__ __forceinline__ unsigned short f2bf_n(float f){
  __hip_bfloat16 h = __float2bfloat16(f);
  return reinterpret_cast<unsigned short&>(h);
}
__device__ __forceinline__ float bf2f(unsigned short u){ return __uint_as_float(((unsigned)u)<<16); }

// compute compressed geometry {w, tx, ty, tz} for (query n, neighbor nb)
__device__ __forceinline__ float4 geo_compute(const float* __restrict__ pos2, int n, int nb){
  const float R = 0.5f * (float)(1.5*6.0*0.025);
  float x = (pos2[nb*3+0]-pos2[n*3+0])/R;
  float y = (pos2[nb*3+1]-pos2[n*3+1])/R;
  float z = (pos2[nb*3+2]-pos2[n*3+2])/R;
  float sq = x*x+y*y+z*z;
  float wgt = 0.f;
  if (sq < 1.f){ float t1 = 1.f-sq; wgt = t1*t1*t1; }
  if (nb == n) wgt = 0.f;
  const float eps = 1e-8f;
  float norm = sqrtf(sq);
  float sq_xy = x*x+y*y;
  bool polar = 1.25f*z*z > sq_xy;
  float sa = sqrtf(3.f*norm/(norm+fabsf(z)+eps));
  float sb = norm/(sqrtf(sq_xy)+eps);
  float xc = polar ? x*sa : x*sb;
  float yc = polar ? y*sa : y*sb;
  float zc = polar ? sgnf(z)*norm : 1.5f*z;
  if (sq < eps){ xc=x; yc=y; zc=z; }
  float nxy = sqrtf(xc*xc+yc*yc);
  const float fo_pi = (float)(4.0/3.141592653589793);
  float sx = (fabsf(xc)>eps) ? xc : eps;
  float sy = (fabsf(yc)>eps) ? yc : eps;
  float ux = sgnf(xc)*nxy;
  float vv = sgnf(yc)*nxy;
  bool xbig = fabsf(yc) <= fabsf(xc);
  float u = xbig ? ux : vv*fo_pi*atanf(xc/sy);
  float v = xbig ? ux*fo_pi*atanf(yc/sx) : vv;
  if (nxy < eps){ u = xc; v = yc; }
  float tx = fminf(fmaxf((u  + 1.f)*1.5f, 0.f), 3.f);
  float ty = fminf(fmaxf((v  + 1.f)*1.5f, 0.f), 3.f);
  float tz = fminf(fmaxf((zc + 1.f)*1.5f, 0.f), 3.f);
  return make_float4(wgt, tx, ty, tz);
}

__device__ __forceinline__ void corners_from_geo(float4 g, float* gg, int* bb){
  float tx=g.y, ty=g.z, tz=g.w, w=g.x;
  int ix = (int)floorf(tx); ix = ix>2?2:ix;
  int iy = (int)floorf(ty); iy = iy>2?2:iy;
  int iz = (int)floorf(tz); iz = iz>2?2:iz;
  float fx = tx-(float)ix, fy = ty-(float)iy, fz = tz-(float)iz;
  float wxa[2] = {1.f-fx, fx};
  float wya[2] = {1.f-fy, fy};
  float wza[2] = {1.f-fz, fz};
  int b000 = ix*16 + iy*4 + iz;
  #pragma unroll
  for (int cc=0; cc<8; cc++){
    int cx = cc>>2, cy = (cc>>1)&1, cz = cc&1;
    gg[cc] = w * wxa[cx]*wya[cy]*wza[cz];
    bb[cc] = b000 + cx*16 + cy*4 + cz;
  }
}

// ---------------- prep + weight transpose fused ----------------
__global__ __launch_bounds__(256) void k_prepw(const float* __restrict__ pos, const float* __restrict__ vel,
    float* __restrict__ pos2, float* __restrict__ feats4,
    const float* __restrict__ W1, const float* __restrict__ W2,
    unsigned short* __restrict__ WT1, unsigned short* __restrict__ WT2){
  __shared__ unsigned short tile[64][72];
  int t = threadIdx.x;
  if (blockIdx.x < 32){
    int i = blockIdx.x*256 + t;
    const float DT = 0.02f;
    float vx = vel[i*3+0], vy = vel[i*3+1], vz = vel[i*3+2];
    float v2x = vx;
    float v2y = vy + DT*(-9.81f);
    float v2z = vz;
    float px = pos[i*3+0] + (DT*(v2x+vx))*0.5f;
    float py = pos[i*3+1] + (DT*(v2y+vy))*0.5f;
    float pz = pos[i*3+2] + (DT*(v2z+vz))*0.5f;
    pos2[i*3+0]=px; pos2[i*3+1]=py; pos2[i*3+2]=pz;
    feats4[i*4+0]=1.f; feats4[i*4+1]=v2x; feats4[i*4+2]=v2y; feats4[i*4+3]=v2z;
    return;
  }
  int b2 = blockIdx.x - 32;
  const float* W = (b2 < 64) ? W1 : W2;
  unsigned short* WT = (b2 < 64) ? WT1 : WT2;
  int kb = (b2 & 63)*64;
  {
    int co = t&63, kr = t>>6;
    #pragma unroll
    for (int i=0;i<16;i++){
      int k = i*4 + kr;
      tile[co][k] = f2bf(W[(size_t)(kb+k)*64 + co]);
    }
  }
  __syncthreads();
  {
    int kk = t&63, cor = t>>6;
    #pragma unroll
    for (int i=0;i<16;i++){
      int co2 = i*4 + cor;
      WT[(size_t)co2*4096 + kb + kk] = tile[co2][kk];
    }
  }
}

// ---------------- cconv0 + fused geometry ----------------
__global__ __launch_bounds__(256) void k_cconv0(const float* __restrict__ feats4, const int* __restrict__ nbrs,
    const float* __restrict__ pos2, float4* __restrict__ geo,
    const float* __restrict__ W0, const float* __restrict__ b0, float* __restrict__ a0f){
  __shared__ float CWT[4][64][33];
  __shared__ float Xs[4][32][4];
  __shared__ float Ws[8192];
  __shared__ float Bl[4][320];
  int t = threadIdx.x, lane = t&63, w = t>>6;
  int n = blockIdx.x*4 + w;
  #pragma unroll
  for (int i=0;i<32;i++) Ws[i*256+t] = W0[i*256+t];
  {
    float* cw = &CWT[w][0][0];
    #pragma unroll
    for (int i=0;i<33;i++) cw[i*64+lane] = 0.f;
  }
  if (lane < 32){
    int idx = n*KN + lane;
    int nb = nbrs[idx];
    *(float4*)&Xs[w][lane][0] = *(const float4*)(feats4 + (size_t)nb*4);
    float4 g = geo_compute(pos2, n, nb);
    geo[idx] = g;
    float gg[8]; int bb[8];
    corners_from_geo(g, gg, bb);
    __builtin_amdgcn_s_waitcnt(0);
    #pragma unroll
    for (int cc=0;cc<8;cc++) CWT[w][bb[cc]][lane] = gg[cc];
  }
  __syncthreads();
  float bacc0=0.f, bacc1=0.f, bacc2=0.f, bacc3=0.f;
  #pragma unroll 8
  for (int k=0;k<32;k++){
    float cw = CWT[w][lane][k];
    float4 xk = *(float4*)&Xs[w][k][0];
    bacc0 += cw*xk.x; bacc1 += cw*xk.y; bacc2 += cw*xk.z; bacc3 += cw*xk.w;
  }
  Bl[w][lane*5+0]=bacc0; Bl[w][lane*5+1]=bacc1; Bl[w][lane*5+2]=bacc2; Bl[w][lane*5+3]=bacc3;
  __syncthreads();
  {
    int h = lane>>5, co = lane&31;
    float acc = h ? 0.f : b0[co];
    int k0 = h*128;
    #pragma unroll 8
    for (int kk=0;kk<128;kk++){
      int kx = k0+kk;
      acc += Bl[w][(kx>>2)*5 + (kx&3)] * Ws[kx*32+co];
    }
    acc += __shfl_xor(acc, 32);
    if (h == 0) a0f[(size_t)n*32+co] = acc;
  }
}

// ---------------- LN(a0f) twice + bf16 Q1(scaled),K1,V1^T + Q2(scaled) ----------------
__global__ __launch_bounds__(128) void k_lnproj1(const float* __restrict__ a0f,
    const float* __restrict__ lna, const float* __restrict__ lnb,
    const float* __restrict__ selfW, const float* __restrict__ selfb,
    const float* __restrict__ srcW, const float* __restrict__ srcb,
    unsigned short* __restrict__ Qb1, unsigned short* __restrict__ Kb1,
    unsigned short* __restrict__ VT1, unsigned short* __restrict__ Q2b){
  __shared__ float sh[4][2][32];
  int t=threadIdx.x, rr=t>>5, c=t&31;
  int r = blockIdx.x*4+rr;
  float x = a0f[r*32+c];
  float s = x;
  for (int o=16;o;o>>=1) s += __shfl_xor(s,o,32);
  float mu = s*(1.f/32.f);
  float d = x-mu;
  float s2 = d*d;
  for (int o=16;o;o>>=1) s2 += __shfl_xor(s2,o,32);
  float istd = 1.f/(sqrtf(s2*(1.f/31.f))+1e-6f);
  sh[rr][0][c] = lna[c]*d*istd + lnb[c];
  sh[rr][1][c] = lna[32+c]*d*istd + lnb[32+c];
  __syncthreads();
  float aq = selfb[c], ak = selfb[32+c], av = selfb[64+c], aq2 = srcb[c];
  for (int cc=0;cc<32;cc++){
    float v0 = sh[rr][0][cc], v1 = sh[rr][1][cc];
    aq  += v0*selfW[cc*32+c];
    ak  += v0*selfW[1024+cc*32+c];
    av  += v0*selfW[2048+cc*32+c];
    aq2 += v1*srcW[cc*32+c];
  }
  const float scl = 0.17677669529663687f;
  Qb1[r*32+c] = f2bf(aq*scl);
  Kb1[r*32+c] = f2bf(ak);
  VT1[(size_t)c*8192 + r] = f2bf(av);
  Q2b[r*32+c] = f2bf(aq2*scl);
}

// ---------------- MFMA flash-attention: 64-key staged tiles, fixed-ref softmax, 8 partitions ----------------
__global__ __launch_bounds__(256) void k_attn_mfma(const unsigned short* __restrict__ Qb,
    const unsigned short* __restrict__ Kb, const unsigned short* __restrict__ VT,
    float* __restrict__ Pacc, float* __restrict__ Pml){
  __shared__ unsigned short Ks[2][64][40];
  __shared__ unsigned short Vs[2][32][72];
  __shared__ float Ot[4][16][36];
  int t = threadIdx.x, lane = t&63, w = t>>6;
  int qb = blockIdx.x, kp = blockIdx.y;
  int q0 = qb*64 + w*16;
  int l15 = lane&15, lg = lane>>4;
  short8v qf = *(const short8v*)(Qb + (size_t)(q0+l15)*32 + lg*8);
  f32x4v o0 = {0.f,0.f,0.f,0.f}, o1 = {0.f,0.f,0.f,0.f};
  f32x4v cz = {0.f,0.f,0.f,0.f};
  const float M0 = 8.f;
  float lacc = 0.f;
  int kbase = kp*1024;

#define STAGE(KT, BUF) do {                                                     \
    int _kb = kbase + (KT)*64;                                                  \
    if (t < 128){                                                               \
      int _row = t>>1, _seg = t&1;                                              \
      const unsigned short* _src = Kb + (size_t)(_kb+_row)*32 + _seg*16;        \
      uint4 _u0 = *(const uint4*)_src;                                          \
      uint4 _u1 = *(const uint4*)(_src+8);                                      \
      *(uint4*)&Ks[BUF][_row][_seg*16]   = _u0;                                 \
      *(uint4*)&Ks[BUF][_row][_seg*16+8] = _u1;                                 \
    } else {                                                                    \
      int _tt = t-128; int _dim = _tt>>2, _seg = _tt&3;                         \
      const unsigned short* _src = VT + (size_t)_dim*8192 + _kb + _seg*16;      \
      uint4 _u0 = *(const uint4*)_src;                                          \
      uint4 _u1 = *(const uint4*)(_src+8);                                      \
      *(uint4*)&Vs[BUF][_dim][_seg*16]   = _u0;                                 \
      *(uint4*)&Vs[BUF][_dim][_seg*16+8] = _u1;                                 \
    }                                                                           \
  } while(0)

  STAGE(0, 0);
  __syncthreads();
  for (int kt=0; kt<16; kt++){
    int b = kt&1;
    if (kt < 15) STAGE(kt+1, b^1);
    #pragma unroll
    for (int h=0; h<2; h++){
      int kk = h*32;
      short8v kf0 = *(const short8v*)&Ks[b][kk+l15][lg*8];
      short8v kf1 = *(const short8v*)&Ks[b][kk+16+l15][lg*8];
      short4v v0a = *(const short4v*)&Vs[b][l15][kk+lg*4];
      short4v v0b = *(const short4v*)&Vs[b][l15][kk+16+lg*4];
      short4v v1a = *(const short4v*)&Vs[b][16+l15][kk+lg*4];
      short4v v1b = *(const short4v*)&Vs[b][16+l15][kk+16+lg*4];
      f32x4v sa = __builtin_amdgcn_mfma_f32_16x16x32_bf16(kf0, qf, cz, 0,0,0);
      f32x4v sb = __builtin_amdgcn_mfma_f32_16x16x32_bf16(kf1, qf, cz, 0,0,0);
      float p0 = __expf(fminf(sa[0]-M0, 30.f)), p1 = __expf(fminf(sa[1]-M0, 30.f));
      float p2 = __expf(fminf(sa[2]-M0, 30.f)), p3 = __expf(fminf(sa[3]-M0, 30.f));
      float p4 = __expf(fminf(sb[0]-M0, 30.f)), p5 = __expf(fminf(sb[1]-M0, 30.f));
      float p6 = __expf(fminf(sb[2]-M0, 30.f)), p7 = __expf(fminf(sb[3]-M0, 30.f));
      lacc += (p0+p1)+(p2+p3)+(p4+p5)+(p6+p7);
      ushort4 ppa, ppb;
      ppa.x = f2bf_n(p0); ppa.y = f2bf_n(p1); ppa.z = f2bf_n(p2); ppa.w = f2bf_n(p3);
      ppb.x = f2bf_n(p4); ppb.y = f2bf_n(p5); ppb.z = f2bf_n(p6); ppb.w = f2bf_n(p7);
      short4v pfa = *(short4v*)&ppa;
      short4v pfb = *(short4v*)&ppb;
      o0 = __builtin_amdgcn_mfma_f32_16x16x16bf16_1k(v0a, pfa, o0, 0,0,0);
      o0 = __builtin_amdgcn_mfma_f32_16x16x16bf16_1k(v0b, pfb, o0, 0,0,0);
      o1 = __builtin_amdgcn_mfma_f32_16x16x16bf16_1k(v1a, pfa, o1, 0,0,0);
      o1 = __builtin_amdgcn_mfma_f32_16x16x16bf16_1k(v1b, pfb, o1, 0,0,0);
    }
    __syncthreads();
  }
#undef STAGE
  lacc += __shfl_xor(lacc, 16);
  lacc += __shfl_xor(lacc, 32);
  #pragma unroll
  for (int r=0;r<4;r++){
    Ot[w][l15][lg*4+r] = o0[r];
    Ot[w][l15][16+lg*4+r] = o1[r];
  }
  __builtin_amdgcn_s_waitcnt(0);
  {
    size_t pi = ((size_t)(q0+l15)*8 + kp)*32;
    float4 a = *(float4*)&Ot[w][l15][lg*8];
    float4 b = *(float4*)&Ot[w][l15][lg*8+4];
    *(float4*)(Pacc + pi + lg*8)     = a;
    *(float4*)(Pacc + pi + lg*8 + 4) = b;
    if (lg == 0){
      Pml[((size_t)(q0+l15)*8 + kp)*2 + 0] = M0;
      Pml[((size_t)(q0+l15)*8 + kp)*2 + 1] = lacc;
    }
  }
}

// ---------------- merge1 ----------------
__global__ __launch_bounds__(128) void k_merge1(const float* __restrict__ Pacc, const float* __restrict__ Pml,
    const float* __restrict__ resid, const float* __restrict__ Wo, const float* __restrict__ bo,
    const float* __restrict__ srcW, const float* __restrict__ srcb,
    unsigned short* __restrict__ Kb2, unsigned short* __restrict__ VT2){
  __shared__ float sh[4][32];
  __shared__ float shh[4][32];
  int t=threadIdx.x, rr=t>>5, c=t&31;
  int r = blockIdx.x*4+rr;
  float m = -1e30f;
  for (int p=0;p<8;p++) m = fmaxf(m, Pml[(r*8+p)*2]);
  float l = 0.f, a = 0.f;
  for (int p=0;p<8;p++){
    float mp = Pml[(r*8+p)*2], lp = Pml[(r*8+p)*2+1];
    float sc = expf(mp-m);
    l += lp*sc;
    a += Pacc[(r*8+p)*32+c]*sc;
  }
  sh[rr][c] = a/l;
  __syncthreads();
  float acc = bo[c];
  for (int cc=0;cc<32;cc++) acc += sh[rr][cc]*Wo[cc*32+c];
  float h = resid[r*32+c] + acc;
  shh[rr][c] = h;
  __syncthreads();
  float ak = srcb[32+c], av = srcb[64+c];
  for (int cc=0;cc<32;cc++){
    float v = shh[rr][cc];
    ak += v*srcW[1024+cc*32+c];
    av += v*srcW[2048+cc*32+c];
  }
  Kb2[r*32+c] = f2bf(ak);
  VT2[(size_t)c*8192 + r] = f2bf(av);
}

// ---------------- merge2 ----------------
__global__ __launch_bounds__(128) void k_merge2(const float* __restrict__ Pacc, const float* __restrict__ Pml,
    const float* __restrict__ resid, const float* __restrict__ Wo, const float* __restrict__ bo,
    const float* __restrict__ lna, const float* __restrict__ lnb,
    const float* __restrict__ w1, const float* __restrict__ b1,
    const float* __restrict__ w2, const float* __restrict__ b2, float* __restrict__ x0){
  __shared__ float sh[4][32];
  __shared__ float sh2[4][64];
  int t=threadIdx.x, rr=t>>5, c=t&31;
  int r = blockIdx.x*4+rr;
  float m = -1e30f;
  for (int p=0;p<8;p++) m = fmaxf(m, Pml[(r*8+p)*2]);
  float l = 0.f, a = 0.f;
  for (int p=0;p<8;p++){
    float mp = Pml[(r*8+p)*2], lp = Pml[(r*8+p)*2+1];
    float sc = expf(mp-m);
    l += lp*sc;
    a += Pacc[(r*8+p)*32+c]*sc;
  }
  sh[rr][c] = a/l;
  __syncthreads();
  float acc = bo[c];
  for (int cc=0;cc<32;cc++) acc += sh[rr][cc]*Wo[cc*32+c];
  float x = resid[r*32+c] + acc;      // h2
  __syncthreads();
  float s = x;
  for (int o=16;o;o>>=1) s += __shfl_xor(s,o,32);
  float mu = s*(1.f/32.f);
  float d = x-mu;
  float s2 = d*d;
  for (int o=16;o;o>>=1) s2 += __shfl_xor(s2,o,32);
  float istd = 1.f/(sqrtf(s2*(1.f/31.f))+1e-6f);
  sh[rr][c] = lna[64+c]*d*istd + lnb[64+c];
  __syncthreads();
  #pragma unroll
  for (int jj=0;jj<2;jj++){
    int j = c + jj*32;
    float h = b1[j];
    for (int cc=0;cc<32;cc++) h += sh[rr][cc]*w1[cc*64+j];
    sh2[rr][j] = fmaxf(h, 0.f);
  }
  __syncthreads();
  #pragma unroll
  for (int jj=0;jj<2;jj++){
    int j = c + jj*32;
    float o = b2[j];
    for (int kk=0;kk<64;kk++) o += sh2[rr][kk]*w2[kk*64+j];
    x0[r*64+j] = o;
  }
}

// ---------------- build B via MFMA (atomic-free), full NP ----------------
__global__ __launch_bounds__(256) void k_build(const float* __restrict__ xin, const int* __restrict__ nbrs,
    const float4* __restrict__ geo, unsigned short* __restrict__ Bg){
  __shared__ unsigned short XT[4][2560];
  __shared__ unsigned short CWT[4][2560];
  int t = threadIdx.x, lane = t&63, w = t>>6;
  int n = blockIdx.x*4 + w;
  unsigned short* xt = XT[w];
  unsigned short* cwt = CWT[w];
  #pragma unroll
  for (int i=0;i<5;i++) ((uint4*)cwt)[i*64+lane] = make_uint4(0u,0u,0u,0u);
  int nreg = 0; float4 g = make_float4(0.f,0.f,0.f,0.f);
  if (lane < 32){
    nreg = nbrs[n*KN + lane];
    g = geo[(size_t)n*KN + lane];
  }
  float xv[32];
  #pragma unroll
  for (int k=0;k<32;k++){
    int nb = __shfl(nreg, k);
    xv[k] = xin[(size_t)nb*64 + lane];
  }
  #pragma unroll
  for (int k2=0;k2<16;k2++){
    unsigned lo = f2bf(fmaxf(xv[2*k2],   0.f));
    unsigned hi = f2bf(fmaxf(xv[2*k2+1], 0.f));
    *(unsigned*)&xt[lane*40 + 2*k2] = lo | (hi<<16);
  }
  if (lane < 32){
    float gg[8]; int bb[8];
    corners_from_geo(g, gg, bb);
    #pragma unroll
    for (int cc=0;cc<8;cc++) cwt[bb[cc]*40 + lane] = f2bf(gg[cc]);
  }
  int l31 = lane&31, lg = lane>>5;
  short8v af[2][2], bf[2][2];
  #pragma unroll
  for (int bt=0;bt<2;bt++)
    #pragma unroll
    for (int kc=0;kc<2;kc++)
      af[bt][kc] = *(short8v*)&cwt[(bt*32+l31)*40 + kc*16 + lg*8];
  #pragma unroll
  for (int ct=0;ct<2;ct++)
    #pragma unroll
    for (int kc=0;kc<2;kc++)
      bf[ct][kc] = *(short8v*)&xt[(ct*32+l31)*40 + kc*16 + lg*8];
  f32x16v acc[2][2];
  #pragma unroll
  for (int bt=0;bt<2;bt++)
    #pragma unroll
    for (int ct=0;ct<2;ct++){
      f32x16v z = {0.f,0.f,0.f,0.f,0.f,0.f,0.f,0.f,0.f,0.f,0.f,0.f,0.f,0.f,0.f,0.f};
      z = __builtin_amdgcn_mfma_f32_32x32x16_bf16(af[bt][0], bf[ct][0], z, 0,0,0);
      z = __builtin_amdgcn_mfma_f32_32x32x16_bf16(af[bt][1], bf[ct][1], z, 0,0,0);
      acc[bt][ct] = z;
    }
  unsigned short* dst = Bg + (size_t)n*4096;
  #pragma unroll
  for (int bt=0;bt<2;bt++)
    #pragma unroll
    for (int ct=0;ct<2;ct++)
      #pragma unroll
      for (int r=0;r<16;r++){
        int row = (r&3) + 8*(r>>2) + 4*lg;
        dst[(bt*32+row)*64 + ct*32 + l31] = f2bf(acc[bt][ct][r]);
      }
}

// ---------------- fused build + gemm3 + epilogue ----------------
__global__ __launch_bounds__(256) void k_buildgemm3(const float* __restrict__ xin, const int* __restrict__ nbrs,
    const float4* __restrict__ geo, const float* __restrict__ W3,
    const float* __restrict__ cb3, const float* __restrict__ dw3, const float* __restrict__ db3,
    const float* __restrict__ pos, const float* __restrict__ pos2, float* __restrict__ outp){
  __shared__ unsigned short XT[4][2560];
  __shared__ unsigned short CWT[4][2560];
  __shared__ unsigned short W3p[3][4096];
  int t = threadIdx.x, lane = t&63, w = t>>6;
  int n = blockIdx.x*4 + w;
  unsigned short* xt  = XT[w];
  unsigned short* cwt = CWT[w];
  #pragma unroll
  for (int co=0; co<3; co++)
    #pragma unroll
    for (int i=0;i<16;i++){
      int k = t + i*256;
      W3p[co][k] = f2bf(W3[(size_t)k*3 + co]);
    }
  #pragma unroll
  for (int i=0;i<5;i++) ((uint4*)cwt)[i*64+lane] = make_uint4(0u,0u,0u,0u);
  int nreg = 0; float4 g = make_float4(0.f,0.f,0.f,0.f);
  if (lane < 32){
    nreg = nbrs[n*KN + lane];
    g = geo[(size_t)n*KN + lane];
  }
  float xv[32];
  #pragma unroll
  for (int k=0;k<32;k++){
    int nb = __shfl(nreg, k);
    xv[k] = xin[(size_t)nb*64 + lane];
  }
  float xq = fmaxf(xin[(size_t)n*64 + lane], 0.f);
  float3 dwv;
  dwv.x = dw3[lane*3+0]; dwv.y = dw3[lane*3+1]; dwv.z = dw3[lane*3+2];
  #pragma unroll
  for (int k2=0;k2<16;k2++){
    unsigned lo = f2bf(fmaxf(xv[2*k2],   0.f));
    unsigned hi = f2bf(fmaxf(xv[2*k2+1], 0.f));
    *(unsigned*)&xt[lane*40 + 2*k2] = lo | (hi<<16);
  }
  if (lane < 32){
    float gg[8]; int bb[8];
    corners_from_geo(g, gg, bb);
    #pragma unroll
    for (int cc=0;cc<8;cc++) cwt[bb[cc]*40 + lane] = f2bf(gg[cc]);
  }
  __syncthreads();
  int l31 = lane&31, lg = lane>>5;
  short8v af[2][2], bf[2][2];
  #pragma unroll
  for (int bt=0;bt<2;bt++)
    #pragma unroll
    for (int kc=0;kc<2;kc++)
      af[bt][kc] = *(short8v*)&cwt[(bt*32+l31)*40 + kc*16 + lg*8];
  #pragma unroll
  for (int ct=0;ct<2;ct++)
    #pragma unroll
    for (int kc=0;kc<2;kc++)
      bf[ct][kc] = *(short8v*)&xt[(ct*32+l31)*40 + kc*16 + lg*8];
  f32x16v acc[2][2];
  #pragma unroll
  for (int bt=0;bt<2;bt++)
    #pragma unroll
    for (int ct=0;ct<2;ct++){
      f32x16v z = {0.f,0.f,0.f,0.f,0.f,0.f,0.f,0.f,0.f,0.f,0.f,0.f,0.f,0.f,0.f,0.f};
      z = __builtin_amdgcn_mfma_f32_32x32x16_bf16(af[bt][0], bf[ct][0], z, 0,0,0);
      z = __builtin_amdgcn_mfma_f32_32x32x16_bf16(af[bt][1], bf[ct][1], z, 0,0,0);
      acc[bt][ct] = z;
    }
  float y0 = xq*dwv.x, y1 = xq*dwv.y, y2 = xq*dwv.z;
  #pragma unroll
  for (int bt=0;bt<2;bt++)
    #pragma unroll
    for (int ct=0;ct<2;ct++)
      #pragma unroll
      for (int r=0;r<16;r++){
        int row = (r&3) + 8*(r>>2) + 4*lg;
        int k = (bt*32+row)*64 + ct*32 + l31;
        float b = bf2f(f2bf(acc[bt][ct][r]));
        y0 += b * bf2f(W3p[0][k]);
        y1 += b * bf2f(W3p[1][k]);
        y2 += b * bf2f(W3p[2][k]);
      }
  #pragma unroll
  for (int m=1; m<64; m<<=1){
    y0 += __shfl_xor(y0, m);
    y1 += __shfl_xor(y1, m);
    y2 += __shfl_xor(y2, m);
  }
  if (lane < 3){
    int co = lane;
    float y = (co==0 ? y0 : (co==1 ? y1 : y2)) + cb3[co] + db3[co];
    float pc = y*(1.f/128.f);
    float po = pos2[n*3+co] + pc;
    outp[n*3+co] = po;
    outp[NP*3 + n*3+co] = (po - pos[n*3+co]) / 0.02f;
  }
}

// ---------------- gemmB: LDS-staged WT slice (removes 4x redundant L2 reads; 1 global stream/step) ----------------
__global__ __launch_bounds__(256, 2) void k_gemmB(const unsigned short* __restrict__ Bg,
    const unsigned short* __restrict__ WT, float* __restrict__ partial){
  __shared__ unsigned short WTs[64*520];   // [co][512] padded to 520 (bank starts 4*l15%32 -> 2-way, free)
  int t = threadIdx.x, lane = t&63, w = t>>6;
  int qt = blockIdx.x, kh = blockIdx.y;
  int l15 = lane&15, lg = lane>>4;
  int kbase = kh*512;
  // cooperative stage: 64 co x 512 k bf16 = 64 KB, 16 x uint4 per thread
  #pragma unroll
  for (int i=0;i<16;i++){
    int idx = i*256 + t;          // 0..4095 chunks of 8 shorts
    int co = idx >> 6;            // 64 chunks per row
    int kk = (idx & 63)*8;
    *(uint4*)&WTs[co*520 + kk] = *(const uint4*)(WT + (size_t)co*4096 + kbase + kk);
  }
  __syncthreads();
  const unsigned short* arow = Bg + (size_t)(qt*64 + w*16 + l15)*4096 + kbase + lg*8;
  const unsigned short* wls = WTs + (size_t)l15*520 + lg*8;
  f32x4v a0 = {0.f,0.f,0.f,0.f}, a1 = {0.f,0.f,0.f,0.f};
  f32x4v a2 = {0.f,0.f,0.f,0.f}, a3 = {0.f,0.f,0.f,0.f};
  short8v afn = *(const short8v*)(arow);   // 2-deep pipeline on the single global stream
  #pragma unroll
  for (int s=0;s<16;s++){
    short8v af = afn;
    if (s < 15) afn = *(const short8v*)(arow + (s+1)*32);
    short8v b0 = *(const short8v*)(wls + s*32);
    short8v b1 = *(const short8v*)(wls + 16*520 + s*32);
    short8v b2 = *(const short8v*)(wls + 32*520 + s*32);
    short8v b3 = *(const short8v*)(wls + 48*520 + s*32);
    a0 = __builtin_amdgcn_mfma_f32_16x16x32_bf16(af, b0, a0, 0,0,0);
    a1 = __builtin_amdgcn_mfma_f32_16x16x32_bf16(af, b1, a1, 0,0,0);
    a2 = __builtin_amdgcn_mfma_f32_16x16x32_bf16(af, b2, a2, 0,0,0);
    a3 = __builtin_amdgcn_mfma_f32_16x16x32_bf16(af, b3, a3, 0,0,0);
  }
  #pragma unroll
  for (int r=0;r<4;r++){
    int q = qt*64 + w*16 + lg*4 + r;
    float* pp = partial + ((size_t)kh*8192 + q)*64;
    pp[l15]      = a0[r];
    pp[16 + l15] = a1[r];
    pp[32 + l15] = a2[r];
    pp[48 + l15] = a3[r];
  }
}

// ---------------- convep: sum 8 partials ----------------
__global__ __launch_bounds__(256) void k_convep(const float* __restrict__ partial,
    const float* __restrict__ xin, const float* __restrict__ dw, const float* __restrict__ db,
    const float* __restrict__ cb, float* __restrict__ xout){
  __shared__ float dws[4096];
  __shared__ float xs[4][64];
  int t = threadIdx.x;
  int co = t&63, qr = t>>6;
  int n = blockIdx.x*4 + qr;
  #pragma unroll
  for (int i=0;i<4;i++) ((float4*)dws)[i*256+t] = ((const float4*)dw)[i*256+t];
  xs[qr][co] = xin[(size_t)n*64+co];
  __syncthreads();
  float y = cb[co] + db[co];
  #pragma unroll
  for (int h=0;h<8;h++) y += partial[((size_t)h*8192 + n)*64 + co];
  for (int ci=0; ci<64; ci++) y += fmaxf(xs[qr][ci],0.f) * dws[ci*64+co];
  xout[(size_t)n*64+co] = y + xs[qr][co];
}

extern "C" void kernel_launch(void* const* d_in, const int* in_sizes, int n_in,
                              void* d_out, int out_size, void* d_ws, size_t ws_size,
                              hipStream_t stream) {
  const float* pos   = (const float*)d_in[0];
  const float* vel   = (const float*)d_in[1];
  const int*   fn    = (const int*)d_in[4];
  const float* cw0f  = (const float*)d_in[6];
  const float* cb0f  = (const float*)d_in[7];
  const float* cw1   = (const float*)d_in[10];
  const float* cb1   = (const float*)d_in[11];
  const float* cw2   = (const float*)d_in[12];
  const float* cb2   = (const float*)d_in[13];
  const float* cw3   = (const float*)d_in[14];
  const float* cb3   = (const float*)d_in[15];
  const float* dw1   = (const float*)d_in[16];
  const float* db1   = (const float*)d_in[17];
  const float* dw2   = (const float*)d_in[18];
  const float* db2   = (const float*)d_in[19];
  const float* dw3   = (const float*)d_in[20];
  const float* db3   = (const float*)d_in[21];
  const float* selfW = (const float*)d_in[22];
  const float* selfb = (const float*)d_in[23];
  const float* srcW  = (const float*)d_in[24];
  const float* srcb  = (const float*)d_in[25];
  const float* lna   = (const float*)d_in[26];
  const float* lnb   = (const float*)d_in[27];
  const float* ffw1  = (const float*)d_in[28];
  const float* ffb1  = (const float*)d_in[29];
  const float* ffw2  = (const float*)d_in[30];
  const float* ffb2  = (const float*)d_in[31];

  float* ws = (float*)d_ws;
  float* pos2   = ws + 0;
  float* feats4 = ws + 24576;
  float* a0f    = ws + 57344;
  unsigned short* Qb1 = (unsigned short*)(ws + 319488);
  unsigned short* Kb1 = (unsigned short*)(ws + 581632);
  unsigned short* VT1 = (unsigned short*)(ws + 843776);
  unsigned short* Q2b = (unsigned short*)(ws + 1105920);
  unsigned short* Kb2 = (unsigned short*)(ws + 1630208);
  unsigned short* VT2 = (unsigned short*)(ws + 1892352);
  float* Pacc   = ws + 2416640;
  float* Pml    = ws + 6610944;
  float* x0     = ws + 6873088;
  float* x1     = ws + 7397376;
  float* x2     = ws + 7921664;
  float4* geo   = (float4*)(ws + 8445952);
  unsigned short* WT1 = (unsigned short*)(ws + 9494528);
  unsigned short* WT2 = (unsigned short*)(ws + 9625600);
  unsigned short* Bg  = (unsigned short*)(ws + 9756672);
  float* partial = ws + 26533888;

  float* outp = (float*)d_out;

  k_prepw<<<160, 256, 0, stream>>>(pos, vel, pos2, feats4, cw1, cw2, WT1, WT2);
  k_cconv0<<<NP/4, 256, 0, stream>>>(feats4, fn, pos2, geo, cw0f, cb0f, a0f);
  k_lnproj1<<<NP/4, 128, 0, stream>>>(a0f, lna, lnb, selfW, selfb, srcW, srcb, Qb1, Kb1, VT1, Q2b);
  k_attn_mfma<<<dim3(NP/64, 8), 256, 0, stream>>>(Qb1, Kb1, VT1, Pacc, Pml);
  k_merge1<<<NP/4, 128, 0, stream>>>(Pacc, Pml, a0f, selfW+3072, selfb+96, srcW, srcb, Kb2, VT2);
  k_attn_mfma<<<dim3(NP/64, 8), 256, 0, stream>>>(Q2b, Kb2, VT2, Pacc, Pml);
  k_merge2<<<NP/4, 128, 0, stream>>>(Pacc, Pml, a0f, srcW+3072, srcb+96, lna, lnb,
                                     ffw1, ffb1, ffw2, ffb2, x0);

  // layer 1
  k_build<<<NP/4, 256, 0, stream>>>(x0, fn, geo, Bg);
  k_gemmB<<<dim3(128,8), 256, 0, stream>>>(Bg, WT1, partial);
  k_convep<<<NP/4, 256, 0, stream>>>(partial, x0, dw1, db1, cb1, x1);
  // layer 2
  k_build<<<NP/4, 256, 0, stream>>>(x1, fn, geo, Bg);
  k_gemmB<<<dim3(128,8), 256, 0, stream>>>(Bg, WT2, partial);
  k_convep<<<NP/4, 256, 0, stream>>>(partial, x1, dw2, db2, cb2, x2);
  // final layer: fused, no Bg
  k_buildgemm3<<<NP/4, 256, 0, stream>>>(x2, fn, geo, cw3, cb3, dw3, db3, pos, pos2, outp);
}

// Round 27
// 216.481 us; speedup vs baseline: 1.2473x; 1.0200x over previous
//
#include <hip/hip_runtime.h>
#include <hip/hip_bf16.h>
#include <math.h>

#define NP 8192
#define KN 32

typedef __attribute__((ext_vector_type(8))) short short8v;   // 8 bf16
typedef __attribute__((ext_vector_type(4))) short short4v;   // 4 bf16
typedef __attribute__((ext_vector_type(4))) float f32x4v;
typedef __attribute__((ext_vector_type(16))) float f32x16v;

__device__ __forceinline__ float sgnf(float x){ return (x>0.f)?1.f:((x<0.f)?-1.f:0.f); }
__device__ __forceinline__ unsigned short f2bf(float f){
  unsigned u = __float_as_uint(f);
  unsigned r = (u + 0x7FFFu + ((u>>16)&1u)) >> 16;
  return (unsigned short)r;
}
__device__ __forceinline__ unsigned short f2bf_n(float f){
  __hip_bfloat16 h = __float2bfloat16(f);
  return reinterpret_cast<unsigned short&>(h);
}
__device__ __forceinline__ float bf2f(unsigned short u){ return __uint_as_float(((unsigned)u)<<16); }

// compute compressed geometry {w, tx, ty, tz} for (query n, neighbor nb)
__device__ __forceinline__ float4 geo_compute(const float* __restrict__ pos2, int n, int nb){
  const float R = 0.5f * (float)(1.5*6.0*0.025);
  float x = (pos2[nb*3+0]-pos2[n*3+0])/R;
  float y = (pos2[nb*3+1]-pos2[n*3+1])/R;
  float z = (pos2[nb*3+2]-pos2[n*3+2])/R;
  float sq = x*x+y*y+z*z;
  float wgt = 0.f;
  if (sq < 1.f){ float t1 = 1.f-sq; wgt = t1*t1*t1; }
  if (nb == n) wgt = 0.f;
  const float eps = 1e-8f;
  float norm = sqrtf(sq);
  float sq_xy = x*x+y*y;
  bool polar = 1.25f*z*z > sq_xy;
  float sa = sqrtf(3.f*norm/(norm+fabsf(z)+eps));
  float sb = norm/(sqrtf(sq_xy)+eps);
  float xc = polar ? x*sa : x*sb;
  float yc = polar ? y*sa : y*sb;
  float zc = polar ? sgnf(z)*norm : 1.5f*z;
  if (sq < eps){ xc=x; yc=y; zc=z; }
  float nxy = sqrtf(xc*xc+yc*yc);
  const float fo_pi = (float)(4.0/3.141592653589793);
  float sx = (fabsf(xc)>eps) ? xc : eps;
  float sy = (fabsf(yc)>eps) ? yc : eps;
  float ux = sgnf(xc)*nxy;
  float vv = sgnf(yc)*nxy;
  bool xbig = fabsf(yc) <= fabsf(xc);
  float u = xbig ? ux : vv*fo_pi*atanf(xc/sy);
  float v = xbig ? ux*fo_pi*atanf(yc/sx) : vv;
  if (nxy < eps){ u = xc; v = yc; }
  float tx = fminf(fmaxf((u  + 1.f)*1.5f, 0.f), 3.f);
  float ty = fminf(fmaxf((v  + 1.f)*1.5f, 0.f), 3.f);
  float tz = fminf(fmaxf((zc + 1.f)*1.5f, 0.f), 3.f);
  return make_float4(wgt, tx, ty, tz);
}

__device__ __forceinline__ void corners_from_geo(float4 g, float* gg, int* bb){
  float tx=g.y, ty=g.z, tz=g.w, w=g.x;
  int ix = (int)floorf(tx); ix = ix>2?2:ix;
  int iy = (int)floorf(ty); iy = iy>2?2:iy;
  int iz = (int)floorf(tz); iz = iz>2?2:iz;
  float fx = tx-(float)ix, fy = ty-(float)iy, fz = tz-(float)iz;
  float wxa[2] = {1.f-fx, fx};
  float wya[2] = {1.f-fy, fy};
  float wza[2] = {1.f-fz, fz};
  int b000 = ix*16 + iy*4 + iz;
  #pragma unroll
  for (int cc=0; cc<8; cc++){
    int cx = cc>>2, cy = (cc>>1)&1, cz = cc&1;
    gg[cc] = w * wxa[cx]*wya[cy]*wza[cz];
    bb[cc] = b000 + cx*16 + cy*4 + cz;
  }
}

// ---------------- prep + weight transpose fused ----------------
__global__ __launch_bounds__(256) void k_prepw(const float* __restrict__ pos, const float* __restrict__ vel,
    float* __restrict__ pos2, float* __restrict__ feats4,
    const float* __restrict__ W1, const float* __restrict__ W2,
    unsigned short* __restrict__ WT1, unsigned short* __restrict__ WT2){
  __shared__ unsigned short tile[64][72];
  int t = threadIdx.x;
  if (blockIdx.x < 32){
    int i = blockIdx.x*256 + t;
    const float DT = 0.02f;
    float vx = vel[i*3+0], vy = vel[i*3+1], vz = vel[i*3+2];
    float v2x = vx;
    float v2y = vy + DT*(-9.81f);
    float v2z = vz;
    float px = pos[i*3+0] + (DT*(v2x+vx))*0.5f;
    float py = pos[i*3+1] + (DT*(v2y+vy))*0.5f;
    float pz = pos[i*3+2] + (DT*(v2z+vz))*0.5f;
    pos2[i*3+0]=px; pos2[i*3+1]=py; pos2[i*3+2]=pz;
    feats4[i*4+0]=1.f; feats4[i*4+1]=v2x; feats4[i*4+2]=v2y; feats4[i*4+3]=v2z;
    return;
  }
  int b2 = blockIdx.x - 32;
  const float* W = (b2 < 64) ? W1 : W2;
  unsigned short* WT = (b2 < 64) ? WT1 : WT2;
  int kb = (b2 & 63)*64;
  {
    int co = t&63, kr = t>>6;
    #pragma unroll
    for (int i=0;i<16;i++){
      int k = i*4 + kr;
      tile[co][k] = f2bf(W[(size_t)(kb+k)*64 + co]);
    }
  }
  __syncthreads();
  {
    int kk = t&63, cor = t>>6;
    #pragma unroll
    for (int i=0;i<16;i++){
      int co2 = i*4 + cor;
      WT[(size_t)co2*4096 + kb + kk] = tile[co2][kk];
    }
  }
}

// ---------------- cconv0 + fused geometry ----------------
__global__ __launch_bounds__(256) void k_cconv0(const float* __restrict__ feats4, const int* __restrict__ nbrs,
    const float* __restrict__ pos2, float4* __restrict__ geo,
    const float* __restrict__ W0, const float* __restrict__ b0, float* __restrict__ a0f){
  __shared__ float CWT[4][64][33];
  __shared__ float Xs[4][32][4];
  __shared__ float Ws[8192];
  __shared__ float Bl[4][320];
  int t = threadIdx.x, lane = t&63, w = t>>6;
  int n = blockIdx.x*4 + w;
  #pragma unroll
  for (int i=0;i<32;i++) Ws[i*256+t] = W0[i*256+t];
  {
    float* cw = &CWT[w][0][0];
    #pragma unroll
    for (int i=0;i<33;i++) cw[i*64+lane] = 0.f;
  }
  if (lane < 32){
    int idx = n*KN + lane;
    int nb = nbrs[idx];
    *(float4*)&Xs[w][lane][0] = *(const float4*)(feats4 + (size_t)nb*4);
    float4 g = geo_compute(pos2, n, nb);
    geo[idx] = g;
    float gg[8]; int bb[8];
    corners_from_geo(g, gg, bb);
    __builtin_amdgcn_s_waitcnt(0);
    #pragma unroll
    for (int cc=0;cc<8;cc++) CWT[w][bb[cc]][lane] = gg[cc];
  }
  __syncthreads();
  float bacc0=0.f, bacc1=0.f, bacc2=0.f, bacc3=0.f;
  #pragma unroll 8
  for (int k=0;k<32;k++){
    float cw = CWT[w][lane][k];
    float4 xk = *(float4*)&Xs[w][k][0];
    bacc0 += cw*xk.x; bacc1 += cw*xk.y; bacc2 += cw*xk.z; bacc3 += cw*xk.w;
  }
  Bl[w][lane*5+0]=bacc0; Bl[w][lane*5+1]=bacc1; Bl[w][lane*5+2]=bacc2; Bl[w][lane*5+3]=bacc3;
  __syncthreads();
  {
    int h = lane>>5, co = lane&31;
    float acc = h ? 0.f : b0[co];
    int k0 = h*128;
    #pragma unroll 8
    for (int kk=0;kk<128;kk++){
      int kx = k0+kk;
      acc += Bl[w][(kx>>2)*5 + (kx&3)] * Ws[kx*32+co];
    }
    acc += __shfl_xor(acc, 32);
    if (h == 0) a0f[(size_t)n*32+co] = acc;
  }
}

// ---------------- LN(a0f) twice + bf16 Q1(scaled),K1,V1^T + Q2(scaled) ----------------
__global__ __launch_bounds__(128) void k_lnproj1(const float* __restrict__ a0f,
    const float* __restrict__ lna, const float* __restrict__ lnb,
    const float* __restrict__ selfW, const float* __restrict__ selfb,
    const float* __restrict__ srcW, const float* __restrict__ srcb,
    unsigned short* __restrict__ Qb1, unsigned short* __restrict__ Kb1,
    unsigned short* __restrict__ VT1, unsigned short* __restrict__ Q2b){
  __shared__ float sh[4][2][32];
  int t=threadIdx.x, rr=t>>5, c=t&31;
  int r = blockIdx.x*4+rr;
  float x = a0f[r*32+c];
  float s = x;
  for (int o=16;o;o>>=1) s += __shfl_xor(s,o,32);
  float mu = s*(1.f/32.f);
  float d = x-mu;
  float s2 = d*d;
  for (int o=16;o;o>>=1) s2 += __shfl_xor(s2,o,32);
  float istd = 1.f/(sqrtf(s2*(1.f/31.f))+1e-6f);
  sh[rr][0][c] = lna[c]*d*istd + lnb[c];
  sh[rr][1][c] = lna[32+c]*d*istd + lnb[32+c];
  __syncthreads();
  float aq = selfb[c], ak = selfb[32+c], av = selfb[64+c], aq2 = srcb[c];
  for (int cc=0;cc<32;cc++){
    float v0 = sh[rr][0][cc], v1 = sh[rr][1][cc];
    aq  += v0*selfW[cc*32+c];
    ak  += v0*selfW[1024+cc*32+c];
    av  += v0*selfW[2048+cc*32+c];
    aq2 += v1*srcW[cc*32+c];
  }
  const float scl = 0.17677669529663687f;
  Qb1[r*32+c] = f2bf(aq*scl);
  Kb1[r*32+c] = f2bf(ak);
  VT1[(size_t)c*8192 + r] = f2bf(av);
  Q2b[r*32+c] = f2bf(aq2*scl);
}

// ---------------- MFMA flash-attention: 64-key staged tiles, fixed-ref softmax, 8 partitions ----------------
__global__ __launch_bounds__(256) void k_attn_mfma(const unsigned short* __restrict__ Qb,
    const unsigned short* __restrict__ Kb, const unsigned short* __restrict__ VT,
    float* __restrict__ Pacc, float* __restrict__ Pml){
  __shared__ unsigned short Ks[2][64][40];
  __shared__ unsigned short Vs[2][32][72];
  __shared__ float Ot[4][16][36];
  int t = threadIdx.x, lane = t&63, w = t>>6;
  int qb = blockIdx.x, kp = blockIdx.y;
  int q0 = qb*64 + w*16;
  int l15 = lane&15, lg = lane>>4;
  short8v qf = *(const short8v*)(Qb + (size_t)(q0+l15)*32 + lg*8);
  f32x4v o0 = {0.f,0.f,0.f,0.f}, o1 = {0.f,0.f,0.f,0.f};
  f32x4v cz = {0.f,0.f,0.f,0.f};
  const float M0 = 8.f;
  float lacc = 0.f;
  int kbase = kp*1024;

#define STAGE(KT, BUF) do {                                                     \
    int _kb = kbase + (KT)*64;                                                  \
    if (t < 128){                                                               \
      int _row = t>>1, _seg = t&1;                                              \
      const unsigned short* _src = Kb + (size_t)(_kb+_row)*32 + _seg*16;        \
      uint4 _u0 = *(const uint4*)_src;                                          \
      uint4 _u1 = *(const uint4*)(_src+8);                                      \
      *(uint4*)&Ks[BUF][_row][_seg*16]   = _u0;                                 \
      *(uint4*)&Ks[BUF][_row][_seg*16+8] = _u1;                                 \
    } else {                                                                    \
      int _tt = t-128; int _dim = _tt>>2, _seg = _tt&3;                         \
      const unsigned short* _src = VT + (size_t)_dim*8192 + _kb + _seg*16;      \
      uint4 _u0 = *(const uint4*)_src;                                          \
      uint4 _u1 = *(const uint4*)(_src+8);                                      \
      *(uint4*)&Vs[BUF][_dim][_seg*16]   = _u0;                                 \
      *(uint4*)&Vs[BUF][_dim][_seg*16+8] = _u1;                                 \
    }                                                                           \
  } while(0)

  STAGE(0, 0);
  __syncthreads();
  for (int kt=0; kt<16; kt++){
    int b = kt&1;
    if (kt < 15) STAGE(kt+1, b^1);
    #pragma unroll
    for (int h=0; h<2; h++){
      int kk = h*32;
      short8v kf0 = *(const short8v*)&Ks[b][kk+l15][lg*8];
      short8v kf1 = *(const short8v*)&Ks[b][kk+16+l15][lg*8];
      short4v v0a = *(const short4v*)&Vs[b][l15][kk+lg*4];
      short4v v0b = *(const short4v*)&Vs[b][l15][kk+16+lg*4];
      short4v v1a = *(const short4v*)&Vs[b][16+l15][kk+lg*4];
      short4v v1b = *(const short4v*)&Vs[b][16+l15][kk+16+lg*4];
      f32x4v sa = __builtin_amdgcn_mfma_f32_16x16x32_bf16(kf0, qf, cz, 0,0,0);
      f32x4v sb = __builtin_amdgcn_mfma_f32_16x16x32_bf16(kf1, qf, cz, 0,0,0);
      float p0 = __expf(fminf(sa[0]-M0, 30.f)), p1 = __expf(fminf(sa[1]-M0, 30.f));
      float p2 = __expf(fminf(sa[2]-M0, 30.f)), p3 = __expf(fminf(sa[3]-M0, 30.f));
      float p4 = __expf(fminf(sb[0]-M0, 30.f)), p5 = __expf(fminf(sb[1]-M0, 30.f));
      float p6 = __expf(fminf(sb[2]-M0, 30.f)), p7 = __expf(fminf(sb[3]-M0, 30.f));
      lacc += (p0+p1)+(p2+p3)+(p4+p5)+(p6+p7);
      ushort4 ppa, ppb;
      ppa.x = f2bf_n(p0); ppa.y = f2bf_n(p1); ppa.z = f2bf_n(p2); ppa.w = f2bf_n(p3);
      ppb.x = f2bf_n(p4); ppb.y = f2bf_n(p5); ppb.z = f2bf_n(p6); ppb.w = f2bf_n(p7);
      short4v pfa = *(short4v*)&ppa;
      short4v pfb = *(short4v*)&ppb;
      o0 = __builtin_amdgcn_mfma_f32_16x16x16bf16_1k(v0a, pfa, o0, 0,0,0);
      o0 = __builtin_amdgcn_mfma_f32_16x16x16bf16_1k(v0b, pfb, o0, 0,0,0);
      o1 = __builtin_amdgcn_mfma_f32_16x16x16bf16_1k(v1a, pfa, o1, 0,0,0);
      o1 = __builtin_amdgcn_mfma_f32_16x16x16bf16_1k(v1b, pfb, o1, 0,0,0);
    }
    __syncthreads();
  }
#undef STAGE
  lacc += __shfl_xor(lacc, 16);
  lacc += __shfl_xor(lacc, 32);
  #pragma unroll
  for (int r=0;r<4;r++){
    Ot[w][l15][lg*4+r] = o0[r];
    Ot[w][l15][16+lg*4+r] = o1[r];
  }
  __builtin_amdgcn_s_waitcnt(0);
  {
    size_t pi = ((size_t)(q0+l15)*8 + kp)*32;
    float4 a = *(float4*)&Ot[w][l15][lg*8];
    float4 b = *(float4*)&Ot[w][l15][lg*8+4];
    *(float4*)(Pacc + pi + lg*8)     = a;
    *(float4*)(Pacc + pi + lg*8 + 4) = b;
    if (lg == 0){
      Pml[((size_t)(q0+l15)*8 + kp)*2 + 0] = M0;
      Pml[((size_t)(q0+l15)*8 + kp)*2 + 1] = lacc;
    }
  }
}

// ---------------- merge1 ----------------
__global__ __launch_bounds__(128) void k_merge1(const float* __restrict__ Pacc, const float* __restrict__ Pml,
    const float* __restrict__ resid, const float* __restrict__ Wo, const float* __restrict__ bo,
    const float* __restrict__ srcW, const float* __restrict__ srcb,
    unsigned short* __restrict__ Kb2, unsigned short* __restrict__ VT2){
  __shared__ float sh[4][32];
  __shared__ float shh[4][32];
  int t=threadIdx.x, rr=t>>5, c=t&31;
  int r = blockIdx.x*4+rr;
  float m = -1e30f;
  for (int p=0;p<8;p++) m = fmaxf(m, Pml[(r*8+p)*2]);
  float l = 0.f, a = 0.f;
  for (int p=0;p<8;p++){
    float mp = Pml[(r*8+p)*2], lp = Pml[(r*8+p)*2+1];
    float sc = expf(mp-m);
    l += lp*sc;
    a += Pacc[(r*8+p)*32+c]*sc;
  }
  sh[rr][c] = a/l;
  __syncthreads();
  float acc = bo[c];
  for (int cc=0;cc<32;cc++) acc += sh[rr][cc]*Wo[cc*32+c];
  float h = resid[r*32+c] + acc;
  shh[rr][c] = h;
  __syncthreads();
  float ak = srcb[32+c], av = srcb[64+c];
  for (int cc=0;cc<32;cc++){
    float v = shh[rr][cc];
    ak += v*srcW[1024+cc*32+c];
    av += v*srcW[2048+cc*32+c];
  }
  Kb2[r*32+c] = f2bf(ak);
  VT2[(size_t)c*8192 + r] = f2bf(av);
}

// ---------------- merge2 ----------------
__global__ __launch_bounds__(128) void k_merge2(const float* __restrict__ Pacc, const float* __restrict__ Pml,
    const float* __restrict__ resid, const float* __restrict__ Wo, const float* __restrict__ bo,
    const float* __restrict__ lna, const float* __restrict__ lnb,
    const float* __restrict__ w1, const float* __restrict__ b1,
    const float* __restrict__ w2, const float* __restrict__ b2, float* __restrict__ x0){
  __shared__ float sh[4][32];
  __shared__ float sh2[4][64];
  int t=threadIdx.x, rr=t>>5, c=t&31;
  int r = blockIdx.x*4+rr;
  float m = -1e30f;
  for (int p=0;p<8;p++) m = fmaxf(m, Pml[(r*8+p)*2]);
  float l = 0.f, a = 0.f;
  for (int p=0;p<8;p++){
    float mp = Pml[(r*8+p)*2], lp = Pml[(r*8+p)*2+1];
    float sc = expf(mp-m);
    l += lp*sc;
    a += Pacc[(r*8+p)*32+c]*sc;
  }
  sh[rr][c] = a/l;
  __syncthreads();
  float acc = bo[c];
  for (int cc=0;cc<32;cc++) acc += sh[rr][cc]*Wo[cc*32+c];
  float x = resid[r*32+c] + acc;      // h2
  __syncthreads();
  float s = x;
  for (int o=16;o;o>>=1) s += __shfl_xor(s,o,32);
  float mu = s*(1.f/32.f);
  float d = x-mu;
  float s2 = d*d;
  for (int o=16;o;o>>=1) s2 += __shfl_xor(s2,o,32);
  float istd = 1.f/(sqrtf(s2*(1.f/31.f))+1e-6f);
  sh[rr][c] = lna[64+c]*d*istd + lnb[64+c];
  __syncthreads();
  #pragma unroll
  for (int jj=0;jj<2;jj++){
    int j = c + jj*32;
    float h = b1[j];
    for (int cc=0;cc<32;cc++) h += sh[rr][cc]*w1[cc*64+j];
    sh2[rr][j] = fmaxf(h, 0.f);
  }
  __syncthreads();
  #pragma unroll
  for (int jj=0;jj<2;jj++){
    int j = c + jj*32;
    float o = b2[j];
    for (int kk=0;kk<64;kk++) o += sh2[rr][kk]*w2[kk*64+j];
    x0[r*64+j] = o;
  }
}

// ---------------- build B via MFMA (atomic-free), full NP ----------------
__global__ __launch_bounds__(256) void k_build(const float* __restrict__ xin, const int* __restrict__ nbrs,
    const float4* __restrict__ geo, unsigned short* __restrict__ Bg){
  __shared__ unsigned short XT[4][2560];
  __shared__ unsigned short CWT[4][2560];
  int t = threadIdx.x, lane = t&63, w = t>>6;
  int n = blockIdx.x*4 + w;
  unsigned short* xt = XT[w];
  unsigned short* cwt = CWT[w];
  #pragma unroll
  for (int i=0;i<5;i++) ((uint4*)cwt)[i*64+lane] = make_uint4(0u,0u,0u,0u);
  int nreg = 0; float4 g = make_float4(0.f,0.f,0.f,0.f);
  if (lane < 32){
    nreg = nbrs[n*KN + lane];
    g = geo[(size_t)n*KN + lane];
  }
  float xv[32];
  #pragma unroll
  for (int k=0;k<32;k++){
    int nb = __shfl(nreg, k);
    xv[k] = xin[(size_t)nb*64 + lane];
  }
  #pragma unroll
  for (int k2=0;k2<16;k2++){
    unsigned lo = f2bf(fmaxf(xv[2*k2],   0.f));
    unsigned hi = f2bf(fmaxf(xv[2*k2+1], 0.f));
    *(unsigned*)&xt[lane*40 + 2*k2] = lo | (hi<<16);
  }
  if (lane < 32){
    float gg[8]; int bb[8];
    corners_from_geo(g, gg, bb);
    #pragma unroll
    for (int cc=0;cc<8;cc++) cwt[bb[cc]*40 + lane] = f2bf(gg[cc]);
  }
  int l31 = lane&31, lg = lane>>5;
  short8v af[2][2], bf[2][2];
  #pragma unroll
  for (int bt=0;bt<2;bt++)
    #pragma unroll
    for (int kc=0;kc<2;kc++)
      af[bt][kc] = *(short8v*)&cwt[(bt*32+l31)*40 + kc*16 + lg*8];
  #pragma unroll
  for (int ct=0;ct<2;ct++)
    #pragma unroll
    for (int kc=0;kc<2;kc++)
      bf[ct][kc] = *(short8v*)&xt[(ct*32+l31)*40 + kc*16 + lg*8];
  f32x16v acc[2][2];
  #pragma unroll
  for (int bt=0;bt<2;bt++)
    #pragma unroll
    for (int ct=0;ct<2;ct++){
      f32x16v z = {0.f,0.f,0.f,0.f,0.f,0.f,0.f,0.f,0.f,0.f,0.f,0.f,0.f,0.f,0.f,0.f};
      z = __builtin_amdgcn_mfma_f32_32x32x16_bf16(af[bt][0], bf[ct][0], z, 0,0,0);
      z = __builtin_amdgcn_mfma_f32_32x32x16_bf16(af[bt][1], bf[ct][1], z, 0,0,0);
      acc[bt][ct] = z;
    }
  unsigned short* dst = Bg + (size_t)n*4096;
  #pragma unroll
  for (int bt=0;bt<2;bt++)
    #pragma unroll
    for (int ct=0;ct<2;ct++)
      #pragma unroll
      for (int r=0;r<16;r++){
        int row = (r&3) + 8*(r>>2) + 4*lg;
        dst[(bt*32+row)*64 + ct*32 + l31] = f2bf(acc[bt][ct][r]);
      }
}

// ---------------- fused build + gemm3 + epilogue ----------------
__global__ __launch_bounds__(256) void k_buildgemm3(const float* __restrict__ xin, const int* __restrict__ nbrs,
    const float4* __restrict__ geo, const float* __restrict__ W3,
    const float* __restrict__ cb3, const float* __restrict__ dw3, const float* __restrict__ db3,
    const float* __restrict__ pos, const float* __restrict__ pos2, float* __restrict__ outp){
  __shared__ unsigned short XT[4][2560];
  __shared__ unsigned short CWT[4][2560];
  __shared__ unsigned short W3p[3][4096];
  int t = threadIdx.x, lane = t&63, w = t>>6;
  int n = blockIdx.x*4 + w;
  unsigned short* xt  = XT[w];
  unsigned short* cwt = CWT[w];
  #pragma unroll
  for (int co=0; co<3; co++)
    #pragma unroll
    for (int i=0;i<16;i++){
      int k = t + i*256;
      W3p[co][k] = f2bf(W3[(size_t)k*3 + co]);
    }
  #pragma unroll
  for (int i=0;i<5;i++) ((uint4*)cwt)[i*64+lane] = make_uint4(0u,0u,0u,0u);
  int nreg = 0; float4 g = make_float4(0.f,0.f,0.f,0.f);
  if (lane < 32){
    nreg = nbrs[n*KN + lane];
    g = geo[(size_t)n*KN + lane];
  }
  float xv[32];
  #pragma unroll
  for (int k=0;k<32;k++){
    int nb = __shfl(nreg, k);
    xv[k] = xin[(size_t)nb*64 + lane];
  }
  float xq = fmaxf(xin[(size_t)n*64 + lane], 0.f);
  float3 dwv;
  dwv.x = dw3[lane*3+0]; dwv.y = dw3[lane*3+1]; dwv.z = dw3[lane*3+2];
  #pragma unroll
  for (int k2=0;k2<16;k2++){
    unsigned lo = f2bf(fmaxf(xv[2*k2],   0.f));
    unsigned hi = f2bf(fmaxf(xv[2*k2+1], 0.f));
    *(unsigned*)&xt[lane*40 + 2*k2] = lo | (hi<<16);
  }
  if (lane < 32){
    float gg[8]; int bb[8];
    corners_from_geo(g, gg, bb);
    #pragma unroll
    for (int cc=0;cc<8;cc++) cwt[bb[cc]*40 + lane] = f2bf(gg[cc]);
  }
  __syncthreads();
  int l31 = lane&31, lg = lane>>5;
  short8v af[2][2], bf[2][2];
  #pragma unroll
  for (int bt=0;bt<2;bt++)
    #pragma unroll
    for (int kc=0;kc<2;kc++)
      af[bt][kc] = *(short8v*)&cwt[(bt*32+l31)*40 + kc*16 + lg*8];
  #pragma unroll
  for (int ct=0;ct<2;ct++)
    #pragma unroll
    for (int kc=0;kc<2;kc++)
      bf[ct][kc] = *(short8v*)&xt[(ct*32+l31)*40 + kc*16 + lg*8];
  f32x16v acc[2][2];
  #pragma unroll
  for (int bt=0;bt<2;bt++)
    #pragma unroll
    for (int ct=0;ct<2;ct++){
      f32x16v z = {0.f,0.f,0.f,0.f,0.f,0.f,0.f,0.f,0.f,0.f,0.f,0.f,0.f,0.f,0.f,0.f};
      z = __builtin_amdgcn_mfma_f32_32x32x16_bf16(af[bt][0], bf[ct][0], z, 0,0,0);
      z = __builtin_amdgcn_mfma_f32_32x32x16_bf16(af[bt][1], bf[ct][1], z, 0,0,0);
      acc[bt][ct] = z;
    }
  float y0 = xq*dwv.x, y1 = xq*dwv.y, y2 = xq*dwv.z;
  #pragma unroll
  for (int bt=0;bt<2;bt++)
    #pragma unroll
    for (int ct=0;ct<2;ct++)
      #pragma unroll
      for (int r=0;r<16;r++){
        int row = (r&3) + 8*(r>>2) + 4*lg;
        int k = (bt*32+row)*64 + ct*32 + l31;
        float b = bf2f(f2bf(acc[bt][ct][r]));
        y0 += b * bf2f(W3p[0][k]);
        y1 += b * bf2f(W3p[1][k]);
        y2 += b * bf2f(W3p[2][k]);
      }
  #pragma unroll
  for (int m=1; m<64; m<<=1){
    y0 += __shfl_xor(y0, m);
    y1 += __shfl_xor(y1, m);
    y2 += __shfl_xor(y2, m);
  }
  if (lane < 3){
    int co = lane;
    float y = (co==0 ? y0 : (co==1 ? y1 : y2)) + cb3[co] + db3[co];
    float pc = y*(1.f/128.f);
    float po = pos2[n*3+co] + pc;
    outp[n*3+co] = po;
    outp[NP*3 + n*3+co] = (po - pos[n*3+co]) / 0.02f;
  }
}

// ---------------- gemmB: LDS-staged WT slice, 128-row q-tile (8 waves) halves staging redundancy ----------------
__global__ __launch_bounds__(512, 2) void k_gemmB(const unsigned short* __restrict__ Bg,
    const unsigned short* __restrict__ WT, float* __restrict__ partial){
  __shared__ unsigned short WTs[64*520];   // [co][512] padded to 520
  int t = threadIdx.x, lane = t&63, w = t>>6;
  int qt = blockIdx.x, kh = blockIdx.y;
  int l15 = lane&15, lg = lane>>4;
  int kbase = kh*512;
  // cooperative stage: 64 co x 512 k bf16 = 64 KB, 8 x uint4 per thread
  #pragma unroll
  for (int i=0;i<8;i++){
    int idx = i*512 + t;          // 0..4095 chunks of 8 shorts
    int co = idx >> 6;
    int kk = (idx & 63)*8;
    *(uint4*)&WTs[co*520 + kk] = *(const uint4*)(WT + (size_t)co*4096 + kbase + kk);
  }
  __syncthreads();
  const unsigned short* arow = Bg + (size_t)(qt*128 + w*16 + l15)*4096 + kbase + lg*8;
  const unsigned short* wls = WTs + (size_t)l15*520 + lg*8;
  f32x4v a0 = {0.f,0.f,0.f,0.f}, a1 = {0.f,0.f,0.f,0.f};
  f32x4v a2 = {0.f,0.f,0.f,0.f}, a3 = {0.f,0.f,0.f,0.f};
  short8v afn = *(const short8v*)(arow);   // 2-deep pipeline on the single global stream
  #pragma unroll
  for (int s=0;s<16;s++){
    short8v af = afn;
    if (s < 15) afn = *(const short8v*)(arow + (s+1)*32);
    short8v b0 = *(const short8v*)(wls + s*32);
    short8v b1 = *(const short8v*)(wls + 16*520 + s*32);
    short8v b2 = *(const short8v*)(wls + 32*520 + s*32);
    short8v b3 = *(const short8v*)(wls + 48*520 + s*32);
    a0 = __builtin_amdgcn_mfma_f32_16x16x32_bf16(af, b0, a0, 0,0,0);
    a1 = __builtin_amdgcn_mfma_f32_16x16x32_bf16(af, b1, a1, 0,0,0);
    a2 = __builtin_amdgcn_mfma_f32_16x16x32_bf16(af, b2, a2, 0,0,0);
    a3 = __builtin_amdgcn_mfma_f32_16x16x32_bf16(af, b3, a3, 0,0,0);
  }
  #pragma unroll
  for (int r=0;r<4;r++){
    int q = qt*128 + w*16 + lg*4 + r;
    float* pp = partial + ((size_t)kh*8192 + q)*64;
    pp[l15]      = a0[r];
    pp[16 + l15] = a1[r];
    pp[32 + l15] = a2[r];
    pp[48 + l15] = a3[r];
  }
}

// ---------------- convep: sum 8 partials ----------------
__global__ __launch_bounds__(256) void k_convep(const float* __restrict__ partial,
    const float* __restrict__ xin, const float* __restrict__ dw, const float* __restrict__ db,
    const float* __restrict__ cb, float* __restrict__ xout){
  __shared__ float dws[4096];
  __shared__ float xs[4][64];
  int t = threadIdx.x;
  int co = t&63, qr = t>>6;
  int n = blockIdx.x*4 + qr;
  #pragma unroll
  for (int i=0;i<4;i++) ((float4*)dws)[i*256+t] = ((const float4*)dw)[i*256+t];
  xs[qr][co] = xin[(size_t)n*64+co];
  __syncthreads();
  float y = cb[co] + db[co];
  #pragma unroll
  for (int h=0;h<8;h++) y += partial[((size_t)h*8192 + n)*64 + co];
  for (int ci=0; ci<64; ci++) y += fmaxf(xs[qr][ci],0.f) * dws[ci*64+co];
  xout[(size_t)n*64+co] = y + xs[qr][co];
}

extern "C" void kernel_launch(void* const* d_in, const int* in_sizes, int n_in,
                              void* d_out, int out_size, void* d_ws, size_t ws_size,
                              hipStream_t stream) {
  const float* pos   = (const float*)d_in[0];
  const float* vel   = (const float*)d_in[1];
  const int*   fn    = (const int*)d_in[4];
  const float* cw0f  = (const float*)d_in[6];
  const float* cb0f  = (const float*)d_in[7];
  const float* cw1   = (const float*)d_in[10];
  const float* cb1   = (const float*)d_in[11];
  const float* cw2   = (const float*)d_in[12];
  const float* cb2   = (const float*)d_in[13];
  const float* cw3   = (const float*)d_in[14];
  const float* cb3   = (const float*)d_in[15];
  const float* dw1   = (const float*)d_in[16];
  const float* db1   = (const float*)d_in[17];
  const float* dw2   = (const float*)d_in[18];
  const float* db2   = (const float*)d_in[19];
  const float* dw3   = (const float*)d_in[20];
  const float* db3   = (const float*)d_in[21];
  const float* selfW = (const float*)d_in[22];
  const float* selfb = (const float*)d_in[23];
  const float* srcW  = (const float*)d_in[24];
  const float* srcb  = (const float*)d_in[25];
  const float* lna   = (const float*)d_in[26];
  const float* lnb   = (const float*)d_in[27];
  const float* ffw1  = (const float*)d_in[28];
  const float* ffb1  = (const float*)d_in[29];
  const float* ffw2  = (const float*)d_in[30];
  const float* ffb2  = (const float*)d_in[31];

  float* ws = (float*)d_ws;
  float* pos2   = ws + 0;
  float* feats4 = ws + 24576;
  float* a0f    = ws + 57344;
  unsigned short* Qb1 = (unsigned short*)(ws + 319488);
  unsigned short* Kb1 = (unsigned short*)(ws + 581632);
  unsigned short* VT1 = (unsigned short*)(ws + 843776);
  unsigned short* Q2b = (unsigned short*)(ws + 1105920);
  unsigned short* Kb2 = (unsigned short*)(ws + 1630208);
  unsigned short* VT2 = (unsigned short*)(ws + 1892352);
  float* Pacc   = ws + 2416640;
  float* Pml    = ws + 6610944;
  float* x0     = ws + 6873088;
  float* x1     = ws + 7397376;
  float* x2     = ws + 7921664;
  float4* geo   = (float4*)(ws + 8445952);
  unsigned short* WT1 = (unsigned short*)(ws + 9494528);
  unsigned short* WT2 = (unsigned short*)(ws + 9625600);
  unsigned short* Bg  = (unsigned short*)(ws + 9756672);
  float* partial = ws + 26533888;

  float* outp = (float*)d_out;

  k_prepw<<<160, 256, 0, stream>>>(pos, vel, pos2, feats4, cw1, cw2, WT1, WT2);
  k_cconv0<<<NP/4, 256, 0, stream>>>(feats4, fn, pos2, geo, cw0f, cb0f, a0f);
  k_lnproj1<<<NP/4, 128, 0, stream>>>(a0f, lna, lnb, selfW, selfb, srcW, srcb, Qb1, Kb1, VT1, Q2b);
  k_attn_mfma<<<dim3(NP/64, 8), 256, 0, stream>>>(Qb1, Kb1, VT1, Pacc, Pml);
  k_merge1<<<NP/4, 128, 0, stream>>>(Pacc, Pml, a0f, selfW+3072, selfb+96, srcW, srcb, Kb2, VT2);
  k_attn_mfma<<<dim3(NP/64, 8), 256, 0, stream>>>(Q2b, Kb2, VT2, Pacc, Pml);
  k_merge2<<<NP/4, 128, 0, stream>>>(Pacc, Pml, a0f, srcW+3072, srcb+96, lna, lnb,
                                     ffw1, ffb1, ffw2, ffb2, x0);

  // layer 1
  k_build<<<NP/4, 256, 0, stream>>>(x0, fn, geo, Bg);
  k_gemmB<<<dim3(64,8), 512, 0, stream>>>(Bg, WT1, partial);
  k_convep<<<NP/4, 256, 0, stream>>>(partial, x0, dw1, db1, cb1, x1);
  // layer 2
  k_build<<<NP/4, 256, 0, stream>>>(x1, fn, geo, Bg);
  k_gemmB<<<dim3(64,8), 512, 0, stream>>>(Bg, WT2, partial);
  k_convep<<<NP/4, 256, 0, stream>>>(partial, x1, dw2, db2, cb2, x2);
  // final layer: fused, no Bg
  k_buildgemm3<<<NP/4, 256, 0, stream>>>(x2, fn, geo, cw3, cb3, dw3, db3, pos, pos2, outp);
}